// Round 1
// baseline (212.277 us; speedup 1.0000x reference)
//
#include <hip/hip_runtime.h>
#include <stdint.h>

using bf16x8  = __attribute__((ext_vector_type(8))) short;           // 8 bf16 = 4 VGPR
using f32x4   = __attribute__((ext_vector_type(4))) float;
using ushort8 = __attribute__((ext_vector_type(8))) unsigned short;  // 16B
using ushort4v= __attribute__((ext_vector_type(4))) unsigned short;

__device__ __forceinline__ unsigned short f2bf(float f) {
    union { float f; uint32_t u; } x; x.f = f;
    uint32_t u = x.u;
    uint32_t r = u + 0x7fffu + ((u >> 16) & 1u);   // RNE
    return (unsigned short)(r >> 16);
}

__device__ __forceinline__ f32x4 mfma16(bf16x8 a, bf16x8 b, f32x4 c) {
    return __builtin_amdgcn_mfma_f32_16x16x32_bf16(a, b, c, 0, 0, 0);
}

// ---------------- cast & pack kernels ----------------

__global__ void cast_x_kernel(const float* __restrict__ x, unsigned short* __restrict__ xb) {
    int i = blockIdx.x * 256 + threadIdx.x;            // 4M/4 threads
    using f32x4v = __attribute__((ext_vector_type(4))) float;
    f32x4v v = ((const f32x4v*)x)[i];
    ushort4v o;
    o[0] = f2bf(v[0]); o[1] = f2bf(v[1]); o[2] = f2bf(v[2]); o[3] = f2bf(v[3]);
    ((ushort4v*)xb)[i] = o;
}

// WpT[j][k], j = s*1024 + h*64 + d  (s in {q,k,v}), k = m-dim. src: w_s[h][k][d]
__global__ void pack_wqkv_kernel(const float* __restrict__ wq, const float* __restrict__ wk,
                                 const float* __restrict__ wv, unsigned short* __restrict__ wpT) {
    int idx = blockIdx.x * 256 + threadIdx.x;          // 3072*1024
    int kk = idx & 1023;
    int j  = idx >> 10;
    int s  = j >> 10, rem = j & 1023;
    int hh = rem >> 6, dd = rem & 63;
    const float* src = (s == 0) ? wq : (s == 1) ? wk : wv;
    wpT[idx] = f2bf(src[((size_t)hh * 1024 + kk) * 64 + dd]);
}

// woT[m][k], k = n*64+d. src: w_o flat [n*64+d][m]
__global__ void pack_wo_kernel(const float* __restrict__ wo, unsigned short* __restrict__ woT) {
    int idx = blockIdx.x * 256 + threadIdx.x;          // 1024*1024
    int kk = idx & 1023;
    int m  = idx >> 10;
    woT[idx] = f2bf(wo[(size_t)kk * 1024 + m]);
}

// ---------------- GEMM (A row-major [M][K], BT row-major [N][K]) ----------------
// MODE 0: scatter bf16 into Q/K/V [b][n][l][d]   (M=4096, N=3072, K=1024)
// MODE 1: write fp32 C row-major [M][N]          (M=4096, N=1024, K=1024)

template<int MODE>
__global__ __launch_bounds__(256) void gemm_bt(
    const unsigned short* __restrict__ A,
    const unsigned short* __restrict__ BT,
    float* __restrict__ Cf,
    unsigned short* __restrict__ Q,
    unsigned short* __restrict__ Kq,
    unsigned short* __restrict__ V,
    int M, int N, int K)
{
    __shared__ unsigned short As[128 * 64];
    __shared__ unsigned short Bs[128 * 64];
    const int tid  = threadIdx.x;
    const int lane = tid & 63;
    const int wave = tid >> 6;
    const int wm = wave >> 1, wn = wave & 1;           // 2x2 wave grid, 64x64 per wave
    const int l15 = lane & 15, l4 = lane >> 4;
    const int row0 = blockIdx.y * 128;
    const int col0 = blockIdx.x * 128;

    f32x4 acc[4][4];
#pragma unroll
    for (int i = 0; i < 4; ++i)
#pragma unroll
        for (int j = 0; j < 4; ++j) acc[i][j] = (f32x4){0.f, 0.f, 0.f, 0.f};

    for (int k0 = 0; k0 < K; k0 += 64) {
        __syncthreads();
        // stage A and BT tiles: 1024 chunks of 8 ushorts each, XOR-swizzled (T2)
#pragma unroll
        for (int it = 0; it < 4; ++it) {
            int c  = tid + it * 256;
            int r  = c >> 3, c8 = c & 7;
            int sw = c8 ^ (r & 7);
            ushort8 va = *(const ushort8*)&A[(size_t)(row0 + r) * K + k0 + c8 * 8];
            *(ushort8*)&As[r * 64 + sw * 8] = va;
            ushort8 vb = *(const ushort8*)&BT[(size_t)(col0 + r) * K + k0 + c8 * 8];
            *(ushort8*)&Bs[r * 64 + sw * 8] = vb;
        }
        __syncthreads();
#pragma unroll
        for (int kk = 0; kk < 2; ++kk) {
            bf16x8 af[4], bfr[4];
#pragma unroll
            for (int m = 0; m < 4; ++m) {
                int r   = wm * 64 + m * 16 + l15;
                int blk = (kk * 4 + l4) ^ (r & 7);
                af[m] = *(const bf16x8*)&As[r * 64 + blk * 8];
            }
#pragma unroll
            for (int n = 0; n < 4; ++n) {
                int r   = wn * 64 + n * 16 + l15;
                int blk = (kk * 4 + l4) ^ (r & 7);
                bfr[n] = *(const bf16x8*)&Bs[r * 64 + blk * 8];
            }
#pragma unroll
            for (int m = 0; m < 4; ++m)
#pragma unroll
                for (int n = 0; n < 4; ++n)
                    acc[m][n] = mfma16(af[m], bfr[n], acc[m][n]);
        }
    }

    // epilogue: D element (reg r, lane): row = l4*4+r, col = l15 [m89 layout]
#pragma unroll
    for (int m = 0; m < 4; ++m) {
#pragma unroll
        for (int n = 0; n < 4; ++n) {
#pragma unroll
            for (int r = 0; r < 4; ++r) {
                int gr = row0 + wm * 64 + m * 16 + l4 * 4 + r;
                int gc = col0 + wn * 64 + n * 16 + l15;
                float v = acc[m][n][r];
                if (MODE == 0) {
                    int s = gc >> 10, rem = gc & 1023;
                    int hh = rem >> 6, dd = rem & 63;
                    int bb = gr >> 11, ll = gr & 2047;
                    unsigned short* dst = (s == 0) ? Q : (s == 1) ? Kq : V;
                    dst[(((size_t)bb * 16 + hh) * 2048 + ll) * 64 + dd] = f2bf(v);
                } else {
                    Cf[(size_t)gr * N + gc] = v;
                }
            }
        }
    }
}

// ---------------- flash attention ----------------
// grid: (32 q-tiles, 16 heads, 2 batch). block: 256 thr = 4 waves, 16 q-rows/wave.

__global__ __launch_bounds__(256) void attn_kernel(
    const unsigned short* __restrict__ qb,
    const unsigned short* __restrict__ kb,
    const unsigned short* __restrict__ vb,
    const unsigned char* __restrict__ mask,
    unsigned short* __restrict__ ctxb)
{
    const int qt = blockIdx.x, h = blockIdx.y, b = blockIdx.z;
    const int tid = threadIdx.x;
    const int lane = tid & 63, wave = tid >> 6;
    const int l15 = lane & 15, l4 = lane >> 4;

    __shared__ unsigned short Ksm[64 * 72];      // K tile, +8 pad
    __shared__ unsigned short Vtsm[64 * 72];     // V tile transposed [d][key], +8 pad
    __shared__ unsigned short Psm[4][16 * 72];   // per-wave P staging

    const unsigned short* qh = qb + ((size_t)(b * 16 + h) * 2048) * 64;
    const unsigned short* kh = kb + ((size_t)(b * 16 + h) * 2048) * 64;
    const unsigned short* vh = vb + ((size_t)(b * 16 + h) * 2048) * 64;
    const unsigned char*  mb = mask + (size_t)b * 2048;

    // Q fragments in registers for the whole kernel (row = lane&15, k = l4*8 + 32*kk)
    const int qrow = qt * 64 + wave * 16 + l15;
    bf16x8 aq[2];
    aq[0] = *(const bf16x8*)&qh[(size_t)qrow * 64 + l4 * 8];
    aq[1] = *(const bf16x8*)&qh[(size_t)qrow * 64 + 32 + l4 * 8];

    f32x4 acc[4];                                 // ctx, d-cols 16*dt + l15
#pragma unroll
    for (int i = 0; i < 4; ++i) acc[i] = (f32x4){0.f, 0.f, 0.f, 0.f};
    float m_r[4] = {-1e30f, -1e30f, -1e30f, -1e30f};
    float l_r[4] = {0.f, 0.f, 0.f, 0.f};

    for (int kv0 = 0; kv0 < 2048; kv0 += 64) {
        __syncthreads();
        // stage K (row-major) and V (transposed)
#pragma unroll
        for (int it = 0; it < 2; ++it) {
            int c = tid + it * 256;
            int kr = c >> 3, kc8 = c & 7;
            ushort8 tk = *(const ushort8*)&kh[(size_t)(kv0 + kr) * 64 + kc8 * 8];
            *(ushort8*)&Ksm[kr * 72 + kc8 * 8] = tk;
            int vr = c & 63, vc8 = c >> 6;
            ushort8 tv = *(const ushort8*)&vh[(size_t)(kv0 + vr) * 64 + vc8 * 8];
#pragma unroll
            for (int j = 0; j < 8; ++j) Vtsm[(vc8 * 8 + j) * 72 + vr] = tv[j];
        }
        __syncthreads();

        // S = Q K^T  (16 q-rows x 64 keys per wave)
        f32x4 s[4];
#pragma unroll
        for (int nt = 0; nt < 4; ++nt) {
            f32x4 z = (f32x4){0.f, 0.f, 0.f, 0.f};
            bf16x8 bk0 = *(const bf16x8*)&Ksm[(nt * 16 + l15) * 72 + l4 * 8];
            bf16x8 bk1 = *(const bf16x8*)&Ksm[(nt * 16 + l15) * 72 + 32 + l4 * 8];
            z = mfma16(aq[0], bk0, z);
            z = mfma16(aq[1], bk1, z);
            s[nt] = z;
        }
        // scale + key-padding mask
#pragma unroll
        for (int nt = 0; nt < 4; ++nt) {
            bool msk = mb[kv0 + nt * 16 + l15] != 0;
#pragma unroll
            for (int r = 0; r < 4; ++r) {
                float sv = s[nt][r] * 0.125f;
                s[nt][r] = msk ? -1e9f : sv;
            }
        }
        // online softmax: row max over 64 keys (4 tiles local + 16 lanes)
        float mx[4];
#pragma unroll
        for (int r = 0; r < 4; ++r)
            mx[r] = fmaxf(fmaxf(s[0][r], s[1][r]), fmaxf(s[2][r], s[3][r]));
#pragma unroll
        for (int off = 1; off < 16; off <<= 1)
#pragma unroll
            for (int r = 0; r < 4; ++r)
                mx[r] = fmaxf(mx[r], __shfl_xor(mx[r], off, 16));

        float scl[4];
#pragma unroll
        for (int r = 0; r < 4; ++r) {
            float mn = fmaxf(m_r[r], mx[r]);
            scl[r] = __expf(m_r[r] - mn);
            m_r[r] = mn;
        }
        float rs[4] = {0.f, 0.f, 0.f, 0.f};
#pragma unroll
        for (int nt = 0; nt < 4; ++nt)
#pragma unroll
            for (int r = 0; r < 4; ++r) {
                float p = __expf(s[nt][r] - m_r[r]);
                s[nt][r] = p;
                rs[r] += p;
            }
#pragma unroll
        for (int off = 1; off < 16; off <<= 1)
#pragma unroll
            for (int r = 0; r < 4; ++r)
                rs[r] += __shfl_xor(rs[r], off, 16);
#pragma unroll
        for (int r = 0; r < 4; ++r) l_r[r] = l_r[r] * scl[r] + rs[r];
#pragma unroll
        for (int dt = 0; dt < 4; ++dt)
#pragma unroll
            for (int r = 0; r < 4; ++r) acc[dt][r] *= scl[r];

        // P -> bf16 -> per-wave LDS (to reach A-fragment layout)
#pragma unroll
        for (int nt = 0; nt < 4; ++nt)
#pragma unroll
            for (int r = 0; r < 4; ++r)
                Psm[wave][(l4 * 4 + r) * 72 + nt * 16 + l15] = f2bf(s[nt][r]);

        bf16x8 pa[2];
        pa[0] = *(const bf16x8*)&Psm[wave][l15 * 72 + l4 * 8];
        pa[1] = *(const bf16x8*)&Psm[wave][l15 * 72 + 32 + l4 * 8];
#pragma unroll
        for (int dt = 0; dt < 4; ++dt) {
            bf16x8 bv0 = *(const bf16x8*)&Vtsm[(dt * 16 + l15) * 72 + l4 * 8];
            bf16x8 bv1 = *(const bf16x8*)&Vtsm[(dt * 16 + l15) * 72 + 32 + l4 * 8];
            acc[dt] = mfma16(pa[0], bv0, acc[dt]);
            acc[dt] = mfma16(pa[1], bv1, acc[dt]);
        }
    }

    // epilogue: ctx / l  -> ctxb [b][l][h*64+d] bf16
    const int rowbase = qt * 64 + wave * 16;
#pragma unroll
    for (int dt = 0; dt < 4; ++dt)
#pragma unroll
        for (int r = 0; r < 4; ++r) {
            int row = rowbase + l4 * 4 + r;
            float o = acc[dt][r] / l_r[r];
            ctxb[((size_t)(b * 2048 + row)) * 1024 + h * 64 + dt * 16 + l15] = f2bf(o);
        }
}

// ---------------- launch ----------------

extern "C" void kernel_launch(void* const* d_in, const int* in_sizes, int n_in,
                              void* d_out, int out_size, void* d_ws, size_t ws_size,
                              hipStream_t stream)
{
    const float* x  = (const float*)d_in[0];
    const float* wq = (const float*)d_in[1];
    const float* wk = (const float*)d_in[2];
    const float* wv = (const float*)d_in[3];
    const float* wo = (const float*)d_in[4];
    const unsigned char* mask = (const unsigned char*)d_in[5];
    float* out = (float*)d_out;

    char* ws = (char*)d_ws;
    unsigned short* xb   = (unsigned short*)(ws);                 //  8 MB  [4096][1024]
    unsigned short* wpT  = (unsigned short*)(ws + 8388608);       //  6 MB  [3072][1024]
    unsigned short* woT  = (unsigned short*)(ws + 14680064);      //  2 MB  [1024][1024]
    unsigned short* qb   = (unsigned short*)(ws + 16777216);      //  8 MB  [2][16][2048][64]
    unsigned short* kb   = (unsigned short*)(ws + 25165824);      //  8 MB
    unsigned short* vb   = (unsigned short*)(ws + 33554432);      //  8 MB
    unsigned short* ctxb = (unsigned short*)(ws + 41943040);      //  8 MB  [4096][1024]

    cast_x_kernel   <<<4096, 256, 0, stream>>>(x, xb);
    pack_wqkv_kernel<<<12288, 256, 0, stream>>>(wq, wk, wv, wpT);
    pack_wo_kernel  <<<4096, 256, 0, stream>>>(wo, woT);

    gemm_bt<0><<<dim3(24, 32), 256, 0, stream>>>(xb, wpT, nullptr, qb, kb, vb, 4096, 3072, 1024);
    attn_kernel<<<dim3(32, 16, 2), 256, 0, stream>>>(qb, kb, vb, mask, ctxb);
    gemm_bt<1><<<dim3(8, 32), 256, 0, stream>>>(ctxb, woT, out, nullptr, nullptr, nullptr, 4096, 1024, 1024);
}

// Round 2
// 147.912 us; speedup vs baseline: 1.4352x; 1.4352x over previous
//
#include <hip/hip_runtime.h>
#include <stdint.h>

using bf16x8  = __attribute__((ext_vector_type(8))) short;           // 8 bf16 = 4 VGPR
using f32x4   = __attribute__((ext_vector_type(4))) float;
using f32x16  = __attribute__((ext_vector_type(16))) float;
using ushort8 = __attribute__((ext_vector_type(8))) unsigned short;  // 16B
using ushort4v= __attribute__((ext_vector_type(4))) unsigned short;
using uint2v  = __attribute__((ext_vector_type(2))) unsigned int;

__device__ __forceinline__ unsigned short f2bf(float f) {
    union { float f; uint32_t u; } x; x.f = f;
    uint32_t u = x.u;
    uint32_t r = u + 0x7fffu + ((u >> 16) & 1u);   // RNE
    return (unsigned short)(r >> 16);
}

__device__ __forceinline__ f32x4 mfma16(bf16x8 a, bf16x8 b, f32x4 c) {
    return __builtin_amdgcn_mfma_f32_16x16x32_bf16(a, b, c, 0, 0, 0);
}
__device__ __forceinline__ f32x16 mfma32(bf16x8 a, bf16x8 b, f32x16 c) {
    return __builtin_amdgcn_mfma_f32_32x32x16_bf16(a, b, c, 0, 0, 0);
}

// packed f32x2 -> bf16x2 (RNE), T12 recipe (no builtin on gfx950)
__device__ __forceinline__ unsigned int cvtpk_bf16(float lo, float hi) {
    unsigned int r;
    asm("v_cvt_pk_bf16_f32 %0, %1, %2" : "=v"(r) : "v"(lo), "v"(hi));
    return r;
}
// v_permlane32_swap_b32: new a = [a(lanes0-31) | b(lanes0-31)], new b = [a(lanes32-63) | b(lanes32-63)]
__device__ __forceinline__ void plswap(unsigned int& a, unsigned int& b) {
    asm("v_permlane32_swap_b32 %0, %1" : "+v"(a), "+v"(b));
}

// ---------------- cast & pack kernels ----------------

__global__ void cast_x_kernel(const float* __restrict__ x, unsigned short* __restrict__ xb) {
    int i = blockIdx.x * 256 + threadIdx.x;            // 4M/4 threads
    using f32x4v = __attribute__((ext_vector_type(4))) float;
    f32x4v v = ((const f32x4v*)x)[i];
    ushort4v o;
    o[0] = f2bf(v[0]); o[1] = f2bf(v[1]); o[2] = f2bf(v[2]); o[3] = f2bf(v[3]);
    ((ushort4v*)xb)[i] = o;
}

// WpT[j][k], j = s*1024 + h*64 + d  (s in {q,k,v}), k = m-dim. src: w_s[h][k][d]
__global__ void pack_wqkv_kernel(const float* __restrict__ wq, const float* __restrict__ wk,
                                 const float* __restrict__ wv, unsigned short* __restrict__ wpT) {
    int idx = blockIdx.x * 256 + threadIdx.x;          // 3072*1024
    int kk = idx & 1023;
    int j  = idx >> 10;
    int s  = j >> 10, rem = j & 1023;
    int hh = rem >> 6, dd = rem & 63;
    const float* src = (s == 0) ? wq : (s == 1) ? wk : wv;
    wpT[idx] = f2bf(src[((size_t)hh * 1024 + kk) * 64 + dd]);
}

// woT[m][k], k = n*64+d. src: w_o flat [n*64+d][m]
__global__ void pack_wo_kernel(const float* __restrict__ wo, unsigned short* __restrict__ woT) {
    int idx = blockIdx.x * 256 + threadIdx.x;          // 1024*1024
    int kk = idx & 1023;
    int m  = idx >> 10;
    woT[idx] = f2bf(wo[(size_t)kk * 1024 + m]);
}

// ---------------- GEMM (A row-major [M][K], BT row-major [N][K]) ----------------

template<int MODE>
__global__ __launch_bounds__(256) void gemm_bt(
    const unsigned short* __restrict__ A,
    const unsigned short* __restrict__ BT,
    float* __restrict__ Cf,
    unsigned short* __restrict__ Q,
    unsigned short* __restrict__ Kq,
    unsigned short* __restrict__ V,
    int M, int N, int K)
{
    __shared__ unsigned short As[128 * 64];
    __shared__ unsigned short Bs[128 * 64];
    const int tid  = threadIdx.x;
    const int lane = tid & 63;
    const int wave = tid >> 6;
    const int wm = wave >> 1, wn = wave & 1;           // 2x2 wave grid, 64x64 per wave
    const int l15 = lane & 15, l4 = lane >> 4;
    const int row0 = blockIdx.y * 128;
    const int col0 = blockIdx.x * 128;

    f32x4 acc[4][4];
#pragma unroll
    for (int i = 0; i < 4; ++i)
#pragma unroll
        for (int j = 0; j < 4; ++j) acc[i][j] = (f32x4){0.f, 0.f, 0.f, 0.f};

    for (int k0 = 0; k0 < K; k0 += 64) {
        __syncthreads();
#pragma unroll
        for (int it = 0; it < 4; ++it) {
            int c  = tid + it * 256;
            int r  = c >> 3, c8 = c & 7;
            int sw = c8 ^ (r & 7);
            ushort8 va = *(const ushort8*)&A[(size_t)(row0 + r) * K + k0 + c8 * 8];
            *(ushort8*)&As[r * 64 + sw * 8] = va;
            ushort8 vb = *(const ushort8*)&BT[(size_t)(col0 + r) * K + k0 + c8 * 8];
            *(ushort8*)&Bs[r * 64 + sw * 8] = vb;
        }
        __syncthreads();
#pragma unroll
        for (int kk = 0; kk < 2; ++kk) {
            bf16x8 af[4], bfr[4];
#pragma unroll
            for (int m = 0; m < 4; ++m) {
                int r   = wm * 64 + m * 16 + l15;
                int blk = (kk * 4 + l4) ^ (r & 7);
                af[m] = *(const bf16x8*)&As[r * 64 + blk * 8];
            }
#pragma unroll
            for (int n = 0; n < 4; ++n) {
                int r   = wn * 64 + n * 16 + l15;
                int blk = (kk * 4 + l4) ^ (r & 7);
                bfr[n] = *(const bf16x8*)&Bs[r * 64 + blk * 8];
            }
#pragma unroll
            for (int m = 0; m < 4; ++m)
#pragma unroll
                for (int n = 0; n < 4; ++n)
                    acc[m][n] = mfma16(af[m], bfr[n], acc[m][n]);
        }
    }

#pragma unroll
    for (int m = 0; m < 4; ++m) {
#pragma unroll
        for (int n = 0; n < 4; ++n) {
#pragma unroll
            for (int r = 0; r < 4; ++r) {
                int gr = row0 + wm * 64 + m * 16 + l4 * 4 + r;
                int gc = col0 + wn * 64 + n * 16 + l15;
                float v = acc[m][n][r];
                if (MODE == 0) {
                    int s = gc >> 10, rem = gc & 1023;
                    int hh = rem >> 6, dd = rem & 63;
                    int bb = gr >> 11, ll = gr & 2047;
                    unsigned short* dst = (s == 0) ? Q : (s == 1) ? Kq : V;
                    dst[(((size_t)bb * 16 + hh) * 2048 + ll) * 64 + dd] = f2bf(v);
                } else {
                    Cf[(size_t)gr * N + gc] = v;
                }
            }
        }
    }
}

// ---------------- flash attention, swapped-QK 32x32 (m214/T12 structure) ----------------
// 1-D grid 512 blocks (XCD-swizzled), 256 thr = 4 waves, 32 q-rows/wave, KVBLK=64.

__global__ __launch_bounds__(256) void attn_kernel(
    const unsigned short* __restrict__ qb,
    const unsigned short* __restrict__ kb,
    const unsigned short* __restrict__ vb,
    const unsigned char* __restrict__ mask,
    unsigned short* __restrict__ ctxb)
{
    // bijective XCD swizzle: 512 blocks, 64 per XCD -> 4 consecutive heads per XCD
    const int lg  = blockIdx.x;
    const int swz = ((lg & 7) << 6) | (lg >> 3);
    const int qt = swz & 15, h = (swz >> 4) & 15, b = swz >> 8;

    const int tid  = threadIdx.x;
    const int lane = tid & 63, wave = tid >> 6;
    const int l31  = lane & 31, hi = lane >> 5;

    __shared__ unsigned short smem[8192];   // K tile [0,4096) / Vt tile [4096,8192); epilogue reuses all
    __shared__ int flags[32];

    const size_t hoff = ((size_t)(b * 16 + h)) * 2048 * 64;
    const unsigned short* qh = qb + hoff;
    const unsigned short* kh = kb + hoff;
    const unsigned short* vh = vb + hoff;
    const unsigned char*  mb = mask + (size_t)b * 2048;

    // per-64-key mask "any" flags (wave-uniform fast path; bench mask is all-zero)
    if (tid < 32) flags[tid] = 0;
    __syncthreads();
    {
        uint2v mv = *(const uint2v*)&mb[tid * 8];
        if (mv[0] | mv[1]) flags[tid >> 3] = 1;
    }

    // Q fragments in registers: B-operand of QK^T and col-owner q = l31
    const int qrow = qt * 128 + wave * 32 + l31;
    bf16x8 qf[4];
#pragma unroll
    for (int ki = 0; ki < 4; ++ki)
        qf[ki] = *(const bf16x8*)&qh[(size_t)qrow * 64 + ki * 16 + hi * 8];

    f32x16 accA = {0,0,0,0,0,0,0,0,0,0,0,0,0,0,0,0};   // ctx^T d=0..31 rows
    f32x16 accB = {0,0,0,0,0,0,0,0,0,0,0,0,0,0,0,0};   // ctx^T d=32..63 rows
    float m_r = -1e30f, l_r = 0.f;
    const float SC  = 0.18033688011112042f;            // 0.125 * log2(e)
    const float THR = 44.3614195558365f;               // 8 / SC  (defer-max, p <= 2^8)

    // async staging regs (T14): tile t loaded while tile t-1 computes
    const int krow = tid >> 3, kc16 = tid & 7;         // K: 64 rows x 8 chunks, 2 iters
    const int vr = tid & 63, vc8 = tid >> 6;           // V: by row, transposed on LDS write
    ushort8 kreg[2], vreg[2];
#pragma unroll
    for (int it = 0; it < 2; ++it) {
        kreg[it] = *(const ushort8*)&kh[(size_t)(krow + it * 32) * 64 + kc16 * 8];
        vreg[it] = *(const ushort8*)&vh[(size_t)vr * 64 + (vc8 + it * 4) * 8];
    }

    for (int t = 0; t < 32; ++t) {
        const int kv0 = t * 64;
        __syncthreads();                               // prev tile's LDS reads done (+ flags at t=0)
        // write staged regs -> LDS, XOR-swizzled (T2): ushort idx ^= (row&7)*8
#pragma unroll
        for (int it = 0; it < 2; ++it) {
            int r = krow + it * 32;
            *(ushort8*)&smem[r * 64 + ((kc16 ^ (r & 7)) * 8)] = kreg[it];
            int d0 = (vc8 + it * 4) * 8;
#pragma unroll
            for (int j = 0; j < 8; ++j) {
                int d = d0 + j;
                smem[4096 + d * 64 + (vr ^ ((d & 7) * 8))] = vreg[it][j];
            }
        }
        __syncthreads();
        if (t < 31) {                                  // issue next tile's loads (hide under compute)
            const int kvn = kv0 + 64;
#pragma unroll
            for (int it = 0; it < 2; ++it) {
                kreg[it] = *(const ushort8*)&kh[(size_t)(kvn + krow + it * 32) * 64 + kc16 * 8];
                vreg[it] = *(const ushort8*)&vh[(size_t)(kvn + vr) * 64 + (vc8 + it * 4) * 8];
            }
        }

        // ---- S^T = K @ Q^T : lane owns q=l31, regs = 32 keys ----
        f32x16 s0 = {0,0,0,0,0,0,0,0,0,0,0,0,0,0,0,0};
        f32x16 s1 = {0,0,0,0,0,0,0,0,0,0,0,0,0,0,0,0};
#pragma unroll
        for (int ki = 0; ki < 4; ++ki) {
            int c0 = ((ki * 2 + hi) ^ (l31 & 7)) * 8;
            bf16x8 a0 = *(const bf16x8*)&smem[l31 * 64 + c0];
            bf16x8 a1 = *(const bf16x8*)&smem[(32 + l31) * 64 + c0];
            s0 = mfma32(a0, qf[ki], s0);
            s1 = mfma32(a1, qf[ki], s1);
        }

        // mask slow path (wave-uniform branch; key_local = (r&3)+8*(r>>2)+4*hi)
        if (flags[t]) {
#pragma unroll
            for (int r = 0; r < 16; ++r) {
                int keyl = (r & 3) + 8 * (r >> 2) + 4 * hi;
                if (mb[kv0 + keyl])      s0[r] = -1e30f;
                if (mb[kv0 + 32 + keyl]) s1[r] = -1e30f;
            }
        }

        // ---- online softmax (raw-domain max, exp2 with folded scale) ----
        float mx;
        {
            float a0 = fmaxf(fmaxf(s0[0], s0[1]),  fmaxf(s0[2],  s0[3]));
            float a1 = fmaxf(fmaxf(s0[4], s0[5]),  fmaxf(s0[6],  s0[7]));
            float a2 = fmaxf(fmaxf(s0[8], s0[9]),  fmaxf(s0[10], s0[11]));
            float a3 = fmaxf(fmaxf(s0[12], s0[13]), fmaxf(s0[14], s0[15]));
            float b0 = fmaxf(fmaxf(s1[0], s1[1]),  fmaxf(s1[2],  s1[3]));
            float b1 = fmaxf(fmaxf(s1[4], s1[5]),  fmaxf(s1[6],  s1[7]));
            float b2 = fmaxf(fmaxf(s1[8], s1[9]),  fmaxf(s1[10], s1[11]));
            float b3 = fmaxf(fmaxf(s1[12], s1[13]), fmaxf(s1[14], s1[15]));
            mx = fmaxf(fmaxf(fmaxf(a0, a1), fmaxf(a2, a3)),
                       fmaxf(fmaxf(b0, b1), fmaxf(b2, b3)));
        }
        mx = fmaxf(mx, __shfl_xor(mx, 32));
        if (__any(mx > m_r + THR)) {                   // defer-max (T13)
            float mn  = fmaxf(m_r, mx);
            float scl = __builtin_amdgcn_exp2f((m_r - mn) * SC);
            m_r = mn;
            l_r *= scl;
#pragma unroll
            for (int i = 0; i < 16; ++i) { accA[i] *= scl; accB[i] *= scl; }
        }
        const float nmc = -m_r * SC;
#pragma unroll
        for (int i = 0; i < 16; ++i) {
            s0[i] = __builtin_amdgcn_exp2f(__builtin_fmaf(s0[i], SC, nmc));
            s1[i] = __builtin_amdgcn_exp2f(__builtin_fmaf(s1[i], SC, nmc));
        }
        // row sum
        float rs;
        {
            float a0 = (s0[0] + s0[1]) + (s0[2] + s0[3]);
            float a1 = (s0[4] + s0[5]) + (s0[6] + s0[7]);
            float a2 = (s0[8] + s0[9]) + (s0[10] + s0[11]);
            float a3 = (s0[12] + s0[13]) + (s0[14] + s0[15]);
            float b0 = (s1[0] + s1[1]) + (s1[2] + s1[3]);
            float b1 = (s1[4] + s1[5]) + (s1[6] + s1[7]);
            float b2 = (s1[8] + s1[9]) + (s1[10] + s1[11]);
            float b3 = (s1[12] + s1[13]) + (s1[14] + s1[15]);
            rs = ((a0 + a1) + (a2 + a3)) + ((b0 + b1) + (b2 + b3));
        }
        rs += __shfl_xor(rs, 32);
        l_r += rs;

        // ---- P -> bf16 B-fragments via cvt_pk + permlane32_swap (T12) ----
        bf16x8 pf[4];
        {
            union { unsigned int u[4]; bf16x8 v; } f;
            unsigned int w0 = cvtpk_bf16(s0[0],  s0[1]),  w1 = cvtpk_bf16(s0[2],  s0[3]);
            unsigned int w2 = cvtpk_bf16(s0[4],  s0[5]),  w3 = cvtpk_bf16(s0[6],  s0[7]);
            unsigned int w4 = cvtpk_bf16(s0[8],  s0[9]),  w5 = cvtpk_bf16(s0[10], s0[11]);
            unsigned int w6 = cvtpk_bf16(s0[12], s0[13]), w7 = cvtpk_bf16(s0[14], s0[15]);
            plswap(w0, w2); plswap(w1, w3); plswap(w4, w6); plswap(w5, w7);
            f.u[0] = w0; f.u[1] = w1; f.u[2] = w2; f.u[3] = w3; pf[0] = f.v;
            f.u[0] = w4; f.u[1] = w5; f.u[2] = w6; f.u[3] = w7; pf[1] = f.v;
            unsigned int x0 = cvtpk_bf16(s1[0],  s1[1]),  x1 = cvtpk_bf16(s1[2],  s1[3]);
            unsigned int x2 = cvtpk_bf16(s1[4],  s1[5]),  x3 = cvtpk_bf16(s1[6],  s1[7]);
            unsigned int x4 = cvtpk_bf16(s1[8],  s1[9]),  x5 = cvtpk_bf16(s1[10], s1[11]);
            unsigned int x6 = cvtpk_bf16(s1[12], s1[13]), x7 = cvtpk_bf16(s1[14], s1[15]);
            plswap(x0, x2); plswap(x1, x3); plswap(x4, x6); plswap(x5, x7);
            f.u[0] = x0; f.u[1] = x1; f.u[2] = x2; f.u[3] = x3; pf[2] = f.v;
            f.u[0] = x4; f.u[1] = x5; f.u[2] = x6; f.u[3] = x7; pf[3] = f.v;
        }

        // ---- ctx^T += V^T @ P^T ----
#pragma unroll
        for (int ks = 0; ks < 4; ++ks) {
            int c0 = ((ks * 2 + hi) ^ (l31 & 7)) * 8;
            bf16x8 vA = *(const bf16x8*)&smem[4096 + l31 * 64 + c0];
            bf16x8 vB = *(const bf16x8*)&smem[4096 + (32 + l31) * 64 + c0];
            accA = mfma32(vA, pf[ks], accA);
            accB = mfma32(vB, pf[ks], accB);
        }
    }

    // ---- epilogue: normalize, LDS transpose, coalesced bf16 store ----
    __syncthreads();
    const float inv = 1.0f / l_r;
    const int qloc = wave * 32 + l31;
#pragma unroll
    for (int r = 0; r < 16; ++r) {
        int dA = (r & 3) + 8 * (r >> 2) + 4 * hi;
        smem[qloc * 64 + (dA ^ ((qloc & 7) * 8))]        = f2bf(accA[r] * inv);
        smem[qloc * 64 + ((32 + dA) ^ ((qloc & 7) * 8))] = f2bf(accB[r] * inv);
    }
    __syncthreads();
#pragma unroll
    for (int it = 0; it < 4; ++it) {
        int idx = tid + it * 256;
        int q = idx >> 3, c = idx & 7;
        ushort8 vv = *(const ushort8*)&smem[q * 64 + ((c * 8) ^ ((q & 7) * 8))];
        *(ushort8*)&ctxb[((size_t)(b * 2048 + qt * 128 + q)) * 1024 + h * 64 + c * 8] = vv;
    }
}

// ---------------- launch ----------------

extern "C" void kernel_launch(void* const* d_in, const int* in_sizes, int n_in,
                              void* d_out, int out_size, void* d_ws, size_t ws_size,
                              hipStream_t stream)
{
    const float* x  = (const float*)d_in[0];
    const float* wq = (const float*)d_in[1];
    const float* wk = (const float*)d_in[2];
    const float* wv = (const float*)d_in[3];
    const float* wo = (const float*)d_in[4];
    const unsigned char* mask = (const unsigned char*)d_in[5];
    float* out = (float*)d_out;

    char* ws = (char*)d_ws;
    unsigned short* xb   = (unsigned short*)(ws);                 //  8 MB  [4096][1024]
    unsigned short* wpT  = (unsigned short*)(ws + 8388608);       //  6 MB  [3072][1024]
    unsigned short* woT  = (unsigned short*)(ws + 14680064);      //  2 MB  [1024][1024]
    unsigned short* qb   = (unsigned short*)(ws + 16777216);      //  8 MB  [2][16][2048][64]
    unsigned short* kb   = (unsigned short*)(ws + 25165824);      //  8 MB
    unsigned short* vb   = (unsigned short*)(ws + 33554432);      //  8 MB
    unsigned short* ctxb = (unsigned short*)(ws + 41943040);      //  8 MB  [4096][1024]

    cast_x_kernel   <<<4096, 256, 0, stream>>>(x, xb);
    pack_wqkv_kernel<<<12288, 256, 0, stream>>>(wq, wk, wv, wpT);
    pack_wo_kernel  <<<4096, 256, 0, stream>>>(wo, woT);

    gemm_bt<0><<<dim3(24, 32), 256, 0, stream>>>(xb, wpT, nullptr, qb, kb, vb, 4096, 3072, 1024);
    attn_kernel<<<512, 256, 0, stream>>>(qb, kb, vb, mask, ctxb);
    gemm_bt<1><<<dim3(8, 32), 256, 0, stream>>>(ctxb, woT, out, nullptr, nullptr, nullptr, 4096, 1024, 1024);
}

// Round 3
// 144.305 us; speedup vs baseline: 1.4710x; 1.0250x over previous
//
#include <hip/hip_runtime.h>
#include <stdint.h>

using bf16x8  = __attribute__((ext_vector_type(8))) short;           // 8 bf16 = 4 VGPR
using f32x4   = __attribute__((ext_vector_type(4))) float;
using f32x16  = __attribute__((ext_vector_type(16))) float;
using ushort8 = __attribute__((ext_vector_type(8))) unsigned short;  // 16B
using ushort4v= __attribute__((ext_vector_type(4))) unsigned short;
using uint2v  = __attribute__((ext_vector_type(2))) unsigned int;

typedef __attribute__((address_space(1))) const unsigned int* gas_ptr;
typedef __attribute__((address_space(3))) unsigned int*       las_ptr;

__device__ __forceinline__ void gload_lds16(const unsigned short* g, unsigned short* l) {
    // async global->LDS, 16B per lane; LDS dest = wave-uniform base + lane*16
    __builtin_amdgcn_global_load_lds((gas_ptr)(const void*)g, (las_ptr)(void*)l, 16, 0, 0);
}

__device__ __forceinline__ unsigned short f2bf(float f) {
    union { float f; uint32_t u; } x; x.f = f;
    uint32_t u = x.u;
    uint32_t r = u + 0x7fffu + ((u >> 16) & 1u);   // RNE
    return (unsigned short)(r >> 16);
}

__device__ __forceinline__ f32x4 mfma16(bf16x8 a, bf16x8 b, f32x4 c) {
    return __builtin_amdgcn_mfma_f32_16x16x32_bf16(a, b, c, 0, 0, 0);
}
__device__ __forceinline__ f32x16 mfma32(bf16x8 a, bf16x8 b, f32x16 c) {
    return __builtin_amdgcn_mfma_f32_32x32x16_bf16(a, b, c, 0, 0, 0);
}

// packed f32x2 -> bf16x2 (RNE), T12 recipe (no builtin on gfx950)
__device__ __forceinline__ unsigned int cvtpk_bf16(float lo, float hi) {
    unsigned int r;
    asm("v_cvt_pk_bf16_f32 %0, %1, %2" : "=v"(r) : "v"(lo), "v"(hi));
    return r;
}
__device__ __forceinline__ void plswap(unsigned int& a, unsigned int& b) {
    asm("v_permlane32_swap_b32 %0, %1" : "+v"(a), "+v"(b));
}

// ---------------- cast & pack kernels ----------------

__global__ void cast_x_kernel(const float* __restrict__ x, unsigned short* __restrict__ xb) {
    int i = blockIdx.x * 256 + threadIdx.x;
    using f32x4v = __attribute__((ext_vector_type(4))) float;
    f32x4v v = ((const f32x4v*)x)[i];
    ushort4v o;
    o[0] = f2bf(v[0]); o[1] = f2bf(v[1]); o[2] = f2bf(v[2]); o[3] = f2bf(v[3]);
    ((ushort4v*)xb)[i] = o;
}

__global__ void pack_wqkv_kernel(const float* __restrict__ wq, const float* __restrict__ wk,
                                 const float* __restrict__ wv, unsigned short* __restrict__ wpT) {
    int idx = blockIdx.x * 256 + threadIdx.x;          // 3072*1024
    int kk = idx & 1023;
    int j  = idx >> 10;
    int s  = j >> 10, rem = j & 1023;
    int hh = rem >> 6, dd = rem & 63;
    const float* src = (s == 0) ? wq : (s == 1) ? wk : wv;
    wpT[idx] = f2bf(src[((size_t)hh * 1024 + kk) * 64 + dd]);
}

__global__ void pack_wo_kernel(const float* __restrict__ wo, unsigned short* __restrict__ woT) {
    int idx = blockIdx.x * 256 + threadIdx.x;          // 1024*1024
    int kk = idx & 1023;
    int m  = idx >> 10;
    woT[idx] = f2bf(wo[(size_t)kk * 1024 + m]);
}

// ---------------- GEMM (A row-major [M][K], BT row-major [N][K]) ----------------
// global_load_lds staging (m97 recipe), pre-swizzled source + swizzled reads (rule #21).
// MODE 0: BN=128, scatter bf16 into Q/K/V.  MODE 1: BN=64, fp32 C row-major.

template<int MODE, int BN>
__global__ __launch_bounds__(256) void gemm_bt(
    const unsigned short* __restrict__ A,
    const unsigned short* __restrict__ BT,
    float* __restrict__ Cf,
    unsigned short* __restrict__ Q,
    unsigned short* __restrict__ Kq,
    unsigned short* __restrict__ V,
    int M, int N, int K)
{
    constexpr int NF = BN / 32;                         // b-fragments per wave (wave covers BN/2 cols)
    __shared__ unsigned short As[128 * 64];
    __shared__ unsigned short Bs[BN * 64];
    const int tid  = threadIdx.x;
    const int lane = tid & 63;
    const int wave = tid >> 6;
    const int wm = wave >> 1, wn = wave & 1;
    const int l15 = lane & 15, l4 = lane >> 4;
    const int row0 = blockIdx.y * 128;
    const int col0 = blockIdx.x * BN;

    f32x4 acc[4][NF];
#pragma unroll
    for (int i = 0; i < 4; ++i)
#pragma unroll
        for (int j = 0; j < NF; ++j) acc[i][j] = (f32x4){0.f, 0.f, 0.f, 0.f};

    for (int k0 = 0; k0 < K; k0 += 64) {
        __syncthreads();
        // A: 128x64 bf16 = 1024 16B-chunks; chunk c -> row r=c>>3, col8=c&7, LDS linear c*16B.
        // Source pre-swizzled: fetch chunk (c8 ^ (r&7)) so swizzled READ yields linear data.
#pragma unroll
        for (int it = 0; it < 4; ++it) {
            int cb = (it * 4 + wave) * 64;
            int c  = cb + lane;
            int r  = c >> 3, c8 = c & 7;
            int sc8 = c8 ^ (r & 7);
            gload_lds16(&A[(size_t)(row0 + r) * K + k0 + sc8 * 8], &As[cb * 8]);
        }
#pragma unroll
        for (int it = 0; it < NF; ++it) {
            int cb = (it * 4 + wave) * 64;
            int c  = cb + lane;
            int r  = c >> 3, c8 = c & 7;
            int sc8 = c8 ^ (r & 7);
            gload_lds16(&BT[(size_t)(col0 + r) * K + k0 + sc8 * 8], &Bs[cb * 8]);
        }
        __syncthreads();
#pragma unroll
        for (int kk = 0; kk < 2; ++kk) {
            bf16x8 af[4], bfr[NF];
#pragma unroll
            for (int m = 0; m < 4; ++m) {
                int r   = wm * 64 + m * 16 + l15;
                int blk = (kk * 4 + l4) ^ (r & 7);
                af[m] = *(const bf16x8*)&As[r * 64 + blk * 8];
            }
#pragma unroll
            for (int n = 0; n < NF; ++n) {
                int r   = wn * (BN / 2) + n * 16 + l15;
                int blk = (kk * 4 + l4) ^ (r & 7);
                bfr[n] = *(const bf16x8*)&Bs[r * 64 + blk * 8];
            }
#pragma unroll
            for (int m = 0; m < 4; ++m)
#pragma unroll
                for (int n = 0; n < NF; ++n)
                    acc[m][n] = mfma16(af[m], bfr[n], acc[m][n]);
        }
    }

#pragma unroll
    for (int m = 0; m < 4; ++m) {
#pragma unroll
        for (int n = 0; n < NF; ++n) {
#pragma unroll
            for (int r = 0; r < 4; ++r) {
                int gr = row0 + wm * 64 + m * 16 + l4 * 4 + r;
                int gc = col0 + wn * (BN / 2) + n * 16 + l15;
                float v = acc[m][n][r];
                if (MODE == 0) {
                    int s = gc >> 10, rem = gc & 1023;
                    int hh = rem >> 6, dd = rem & 63;
                    int bb = gr >> 11, ll = gr & 2047;
                    unsigned short* dst = (s == 0) ? Q : (s == 1) ? Kq : V;
                    dst[(((size_t)bb * 16 + hh) * 2048 + ll) * 64 + dd] = f2bf(v);
                } else {
                    Cf[(size_t)gr * N + gc] = v;
                }
            }
        }
    }
}

// ---------------- flash attention, swapped-QK 32x32, double-buffered ----------------
// 512 blocks (XCD-swizzled), 256 thr = 4 waves, 32 q-rows/wave, KVBLK=64, 1 barrier/tile.

__global__ __launch_bounds__(256) void attn_kernel(
    const unsigned short* __restrict__ qb,
    const unsigned short* __restrict__ kb,
    const unsigned short* __restrict__ vb,
    const unsigned char* __restrict__ mask,
    unsigned short* __restrict__ ctxb)
{
    const int lg  = blockIdx.x;
    const int swz = ((lg & 7) << 6) | (lg >> 3);
    const int qt = swz & 15, h = (swz >> 4) & 15, b = swz >> 8;

    const int tid  = threadIdx.x;
    const int lane = tid & 63, wave = tid >> 6;
    const int l31  = lane & 31, hi = lane >> 5;

    __shared__ unsigned short smem[16384];  // [0,8K): K buf0/buf1; [8K,16K): Vt buf0/buf1 (ushorts)
    __shared__ int flags[32];

    const size_t hoff = ((size_t)(b * 16 + h)) * 2048 * 64;
    const unsigned short* qh = qb + hoff;
    const unsigned short* kh = kb + hoff;
    const unsigned short* vh = vb + hoff;
    const unsigned char*  mb = mask + (size_t)b * 2048;

    if (tid < 32) flags[tid] = 0;
    __syncthreads();
    {
        uint2v mv = *(const uint2v*)&mb[tid * 8];
        if (mv[0] | mv[1]) flags[tid >> 3] = 1;
    }

    const int qrow = qt * 128 + wave * 32 + l31;
    bf16x8 qf[4];
#pragma unroll
    for (int ki = 0; ki < 4; ++ki)
        qf[ki] = *(const bf16x8*)&qh[(size_t)qrow * 64 + ki * 16 + hi * 8];

    f32x16 accA = {0,0,0,0,0,0,0,0,0,0,0,0,0,0,0,0};
    f32x16 accB = {0,0,0,0,0,0,0,0,0,0,0,0,0,0,0,0};
    float m_r = -1e30f, l_r = 0.f;
    const float SC  = 0.18033688011112042f;            // 0.125 * log2(e)
    const float THR = 44.3614195558365f;               // 8 / SC  (defer-max)

    // staging assignments
    const int krow = tid >> 3, kc16 = tid & 7;         // K: 8 rows x 8 chunks per wave, x2 iters
    const int vd = tid & 63, vcb = (tid >> 6) * 2;     // Vt: lane owns d=vd, chunks vcb..vcb+1

    ushort8 kreg[2];
    unsigned short vreg[16];
#pragma unroll
    for (int it = 0; it < 2; ++it)
        kreg[it] = *(const ushort8*)&kh[(size_t)(krow + it * 32) * 64 + kc16 * 8];
#pragma unroll
    for (int j = 0; j < 16; ++j)                       // coalesced: 64 lanes = one 128B V row
        vreg[j] = vh[(size_t)(vcb * 8 + j) * 64 + vd];

    for (int t = 0; t < 32; ++t) {
        const int kv0 = t * 64;
        unsigned short* Kb = smem + (t & 1) * 4096;
        unsigned short* Vb = smem + 8192 + (t & 1) * 4096;

        // write staged regs -> LDS (XOR-swizzled chunks)
#pragma unroll
        for (int it = 0; it < 2; ++it) {
            int r = krow + it * 32;
            *(ushort8*)&Kb[r * 64 + ((kc16 ^ (r & 7)) * 8)] = kreg[it];
        }
        {
            union { unsigned short u[16]; ushort8 v[2]; } p;
#pragma unroll
            for (int j = 0; j < 16; ++j) p.u[j] = vreg[j];
#pragma unroll
            for (int c = 0; c < 2; ++c) {
                int cc = vcb + c;
                *(ushort8*)&Vb[vd * 64 + ((cc ^ (vd & 7)) * 8)] = p.v[c];
            }
        }
        __syncthreads();                               // only barrier per tile

        if (t < 31) {                                  // issue next tile's loads under compute
            const int kvn = kv0 + 64;
#pragma unroll
            for (int it = 0; it < 2; ++it)
                kreg[it] = *(const ushort8*)&kh[(size_t)(kvn + krow + it * 32) * 64 + kc16 * 8];
#pragma unroll
            for (int j = 0; j < 16; ++j)
                vreg[j] = vh[(size_t)(kvn + vcb * 8 + j) * 64 + vd];
        }

        // ---- S^T = K @ Q^T ----
        f32x16 s0 = {0,0,0,0,0,0,0,0,0,0,0,0,0,0,0,0};
        f32x16 s1 = {0,0,0,0,0,0,0,0,0,0,0,0,0,0,0,0};
        __builtin_amdgcn_s_setprio(1);
#pragma unroll
        for (int ki = 0; ki < 4; ++ki) {
            int c0 = ((ki * 2 + hi) ^ (l31 & 7)) * 8;
            bf16x8 a0 = *(const bf16x8*)&Kb[l31 * 64 + c0];
            bf16x8 a1 = *(const bf16x8*)&Kb[(32 + l31) * 64 + c0];
            s0 = mfma32(a0, qf[ki], s0);
            s1 = mfma32(a1, qf[ki], s1);
        }
        __builtin_amdgcn_s_setprio(0);

        if (flags[t]) {                                // wave-uniform mask slow path
#pragma unroll
            for (int r = 0; r < 16; ++r) {
                int keyl = (r & 3) + 8 * (r >> 2) + 4 * hi;
                if (mb[kv0 + keyl])      s0[r] = -1e30f;
                if (mb[kv0 + 32 + keyl]) s1[r] = -1e30f;
            }
        }

        // ---- online softmax ----
        float mx;
        {
            float a0 = fmaxf(fmaxf(s0[0], s0[1]),  fmaxf(s0[2],  s0[3]));
            float a1 = fmaxf(fmaxf(s0[4], s0[5]),  fmaxf(s0[6],  s0[7]));
            float a2 = fmaxf(fmaxf(s0[8], s0[9]),  fmaxf(s0[10], s0[11]));
            float a3 = fmaxf(fmaxf(s0[12], s0[13]), fmaxf(s0[14], s0[15]));
            float b0 = fmaxf(fmaxf(s1[0], s1[1]),  fmaxf(s1[2],  s1[3]));
            float b1 = fmaxf(fmaxf(s1[4], s1[5]),  fmaxf(s1[6],  s1[7]));
            float b2 = fmaxf(fmaxf(s1[8], s1[9]),  fmaxf(s1[10], s1[11]));
            float b3 = fmaxf(fmaxf(s1[12], s1[13]), fmaxf(s1[14], s1[15]));
            mx = fmaxf(fmaxf(fmaxf(a0, a1), fmaxf(a2, a3)),
                       fmaxf(fmaxf(b0, b1), fmaxf(b2, b3)));
        }
        mx = fmaxf(mx, __shfl_xor(mx, 32));
        if (__any(mx > m_r + THR)) {                   // defer-max (T13)
            float mn  = fmaxf(m_r, mx);
            float scl = __builtin_amdgcn_exp2f((m_r - mn) * SC);
            m_r = mn;
            l_r *= scl;
#pragma unroll
            for (int i = 0; i < 16; ++i) { accA[i] *= scl; accB[i] *= scl; }
        }
        const float nmc = -m_r * SC;
#pragma unroll
        for (int i = 0; i < 16; ++i) {
            s0[i] = __builtin_amdgcn_exp2f(__builtin_fmaf(s0[i], SC, nmc));
            s1[i] = __builtin_amdgcn_exp2f(__builtin_fmaf(s1[i], SC, nmc));
        }
        float rs;
        {
            float a0 = (s0[0] + s0[1]) + (s0[2] + s0[3]);
            float a1 = (s0[4] + s0[5]) + (s0[6] + s0[7]);
            float a2 = (s0[8] + s0[9]) + (s0[10] + s0[11]);
            float a3 = (s0[12] + s0[13]) + (s0[14] + s0[15]);
            float b0 = (s1[0] + s1[1]) + (s1[2] + s1[3]);
            float b1 = (s1[4] + s1[5]) + (s1[6] + s1[7]);
            float b2 = (s1[8] + s1[9]) + (s1[10] + s1[11]);
            float b3 = (s1[12] + s1[13]) + (s1[14] + s1[15]);
            rs = ((a0 + a1) + (a2 + a3)) + ((b0 + b1) + (b2 + b3));
        }
        rs += __shfl_xor(rs, 32);
        l_r += rs;

        // ---- P -> bf16 B-fragments (T12: cvt_pk + permlane32_swap) ----
        bf16x8 pf[4];
        {
            union { unsigned int u[4]; bf16x8 v; } f;
            unsigned int w0 = cvtpk_bf16(s0[0],  s0[1]),  w1 = cvtpk_bf16(s0[2],  s0[3]);
            unsigned int w2 = cvtpk_bf16(s0[4],  s0[5]),  w3 = cvtpk_bf16(s0[6],  s0[7]);
            unsigned int w4 = cvtpk_bf16(s0[8],  s0[9]),  w5 = cvtpk_bf16(s0[10], s0[11]);
            unsigned int w6 = cvtpk_bf16(s0[12], s0[13]), w7 = cvtpk_bf16(s0[14], s0[15]);
            plswap(w0, w2); plswap(w1, w3); plswap(w4, w6); plswap(w5, w7);
            f.u[0] = w0; f.u[1] = w1; f.u[2] = w2; f.u[3] = w3; pf[0] = f.v;
            f.u[0] = w4; f.u[1] = w5; f.u[2] = w6; f.u[3] = w7; pf[1] = f.v;
            unsigned int x0 = cvtpk_bf16(s1[0],  s1[1]),  x1 = cvtpk_bf16(s1[2],  s1[3]);
            unsigned int x2 = cvtpk_bf16(s1[4],  s1[5]),  x3 = cvtpk_bf16(s1[6],  s1[7]);
            unsigned int x4 = cvtpk_bf16(s1[8],  s1[9]),  x5 = cvtpk_bf16(s1[10], s1[11]);
            unsigned int x6 = cvtpk_bf16(s1[12], s1[13]), x7 = cvtpk_bf16(s1[14], s1[15]);
            plswap(x0, x2); plswap(x1, x3); plswap(x4, x6); plswap(x5, x7);
            f.u[0] = x0; f.u[1] = x1; f.u[2] = x2; f.u[3] = x3; pf[2] = f.v;
            f.u[0] = x4; f.u[1] = x5; f.u[2] = x6; f.u[3] = x7; pf[3] = f.v;
        }

        // ---- ctx^T += V^T @ P^T ----
        __builtin_amdgcn_s_setprio(1);
#pragma unroll
        for (int ks = 0; ks < 4; ++ks) {
            int c0 = ((ks * 2 + hi) ^ (l31 & 7)) * 8;
            bf16x8 vA = *(const bf16x8*)&Vb[l31 * 64 + c0];
            bf16x8 vB = *(const bf16x8*)&Vb[(32 + l31) * 64 + c0];
            accA = mfma32(vA, pf[ks], accA);
            accB = mfma32(vB, pf[ks], accB);
        }
        __builtin_amdgcn_s_setprio(0);
    }

    // ---- epilogue: normalize, LDS transpose, coalesced bf16 store ----
    __syncthreads();
    const float inv = 1.0f / l_r;
    const int qloc = wave * 32 + l31;
#pragma unroll
    for (int r = 0; r < 16; ++r) {
        int dA = (r & 3) + 8 * (r >> 2) + 4 * hi;
        smem[qloc * 64 + (dA ^ ((qloc & 7) * 8))]        = f2bf(accA[r] * inv);
        smem[qloc * 64 + ((32 + dA) ^ ((qloc & 7) * 8))] = f2bf(accB[r] * inv);
    }
    __syncthreads();
#pragma unroll
    for (int it = 0; it < 4; ++it) {
        int idx = tid + it * 256;
        int q = idx >> 3, c = idx & 7;
        ushort8 vv = *(const ushort8*)&smem[q * 64 + ((c * 8) ^ ((q & 7) * 8))];
        *(ushort8*)&ctxb[((size_t)(b * 2048 + qt * 128 + q)) * 1024 + h * 64 + c * 8] = vv;
    }
}

// ---------------- launch ----------------

extern "C" void kernel_launch(void* const* d_in, const int* in_sizes, int n_in,
                              void* d_out, int out_size, void* d_ws, size_t ws_size,
                              hipStream_t stream)
{
    const float* x  = (const float*)d_in[0];
    const float* wq = (const float*)d_in[1];
    const float* wk = (const float*)d_in[2];
    const float* wv = (const float*)d_in[3];
    const float* wo = (const float*)d_in[4];
    const unsigned char* mask = (const unsigned char*)d_in[5];
    float* out = (float*)d_out;

    char* ws = (char*)d_ws;
    unsigned short* xb   = (unsigned short*)(ws);                 //  8 MB  [4096][1024]
    unsigned short* wpT  = (unsigned short*)(ws + 8388608);       //  6 MB  [3072][1024]
    unsigned short* woT  = (unsigned short*)(ws + 14680064);      //  2 MB  [1024][1024]
    unsigned short* qb   = (unsigned short*)(ws + 16777216);      //  8 MB  [2][16][2048][64]
    unsigned short* kb   = (unsigned short*)(ws + 25165824);      //  8 MB
    unsigned short* vb   = (unsigned short*)(ws + 33554432);      //  8 MB
    unsigned short* ctxb = (unsigned short*)(ws + 41943040);      //  8 MB  [4096][1024]

    cast_x_kernel   <<<4096, 256, 0, stream>>>(x, xb);
    pack_wqkv_kernel<<<12288, 256, 0, stream>>>(wq, wk, wv, wpT);
    pack_wo_kernel  <<<4096, 256, 0, stream>>>(wo, woT);

    gemm_bt<0,128><<<dim3(24, 32), 256, 0, stream>>>(xb, wpT, nullptr, qb, kb, vb, 4096, 3072, 1024);
    attn_kernel<<<512, 256, 0, stream>>>(qb, kb, vb, mask, ctxb);
    gemm_bt<1,64><<<dim3(16, 32), 256, 0, stream>>>(ctxb, woT, out, nullptr, nullptr, nullptr, 4096, 1024, 1024);
}

// Round 4
// 139.139 us; speedup vs baseline: 1.5256x; 1.0371x over previous
//
#include <hip/hip_runtime.h>
#include <stdint.h>

using bf16x8  = __attribute__((ext_vector_type(8))) short;           // 8 bf16 = 4 VGPR
using f32x4   = __attribute__((ext_vector_type(4))) float;
using f32x16  = __attribute__((ext_vector_type(16))) float;
using ushort8 = __attribute__((ext_vector_type(8))) unsigned short;  // 16B
using ushort4v= __attribute__((ext_vector_type(4))) unsigned short;
using uint2v  = __attribute__((ext_vector_type(2))) unsigned int;

typedef __attribute__((address_space(1))) const unsigned int* gas_ptr;
typedef __attribute__((address_space(3))) unsigned int*       las_ptr;

__device__ __forceinline__ void gload_lds16(const unsigned short* g, unsigned short* l) {
    __builtin_amdgcn_global_load_lds((gas_ptr)(const void*)g, (las_ptr)(void*)l, 16, 0, 0);
}

__device__ __forceinline__ unsigned short f2bf(float f) {
    union { float f; uint32_t u; } x; x.f = f;
    uint32_t u = x.u;
    uint32_t r = u + 0x7fffu + ((u >> 16) & 1u);   // RNE
    return (unsigned short)(r >> 16);
}
__device__ __forceinline__ float bf2f(unsigned short u) {
    union { uint32_t u; float f; } x; x.u = ((uint32_t)u) << 16;
    return x.f;
}

__device__ __forceinline__ f32x4 mfma16(bf16x8 a, bf16x8 b, f32x4 c) {
    return __builtin_amdgcn_mfma_f32_16x16x32_bf16(a, b, c, 0, 0, 0);
}
__device__ __forceinline__ f32x16 mfma32(bf16x8 a, bf16x8 b, f32x16 c) {
    return __builtin_amdgcn_mfma_f32_32x32x16_bf16(a, b, c, 0, 0, 0);
}

__device__ __forceinline__ unsigned int cvtpk_bf16(float lo, float hi) {
    unsigned int r;
    asm("v_cvt_pk_bf16_f32 %0, %1, %2" : "=v"(r) : "v"(lo), "v"(hi));
    return r;
}
__device__ __forceinline__ void plswap(unsigned int& a, unsigned int& b) {
    asm("v_permlane32_swap_b32 %0, %1" : "+v"(a), "+v"(b));
}

// ---------------- cast & pack kernels ----------------

__global__ void cast_x_kernel(const float* __restrict__ x, unsigned short* __restrict__ xb) {
    int i = blockIdx.x * 256 + threadIdx.x;
    using f32x4v = __attribute__((ext_vector_type(4))) float;
    f32x4v v = ((const f32x4v*)x)[i];
    ushort4v o;
    o[0] = f2bf(v[0]); o[1] = f2bf(v[1]); o[2] = f2bf(v[2]); o[3] = f2bf(v[3]);
    ((ushort4v*)xb)[i] = o;
}

// coalesced tiled transpose: w_s[h][k][d] -> wpT[(s*1024+h*64+d)][k]
__global__ void pack_wqkv_t(const float* __restrict__ wq, const float* __restrict__ wk,
                            const float* __restrict__ wv, unsigned short* __restrict__ wpT) {
    __shared__ float tile[64][65];
    const int mm = blockIdx.y;                 // 0..47
    const int s = mm >> 4, hh = mm & 15;
    const float* src = ((s == 0) ? wq : (s == 1) ? wk : wv) + (size_t)hh * 1024 * 64;
    const int k0 = blockIdx.x * 64;
    const int c = threadIdx.x & 63, rg = threadIdx.x >> 6;
#pragma unroll
    for (int i = 0; i < 16; ++i) {
        int r = rg * 16 + i;
        tile[r][c] = src[(size_t)(k0 + r) * 64 + c];
    }
    __syncthreads();
    unsigned short* dst = wpT + ((size_t)s * 1024 + hh * 64) * 1024 + k0;
    const int kc = threadIdx.x & 63, dg = threadIdx.x >> 6;
#pragma unroll
    for (int i = 0; i < 16; ++i) {
        int d = dg * 16 + i;
        dst[(size_t)d * 1024 + kc] = f2bf(tile[kc][d]);
    }
}

// coalesced tiled transpose: wo[k][m] -> woT[m][k]   (k = n*64+d)
__global__ void pack_wo_t(const float* __restrict__ wo, unsigned short* __restrict__ woT) {
    __shared__ float tile[64][65];
    const int r0 = blockIdx.y * 64;            // k
    const int c0 = blockIdx.x * 64;            // m
    const int c = threadIdx.x & 63, rg = threadIdx.x >> 6;
#pragma unroll
    for (int i = 0; i < 16; ++i) {
        int r = rg * 16 + i;
        tile[r][c] = wo[(size_t)(r0 + r) * 1024 + c0 + c];
    }
    __syncthreads();
    const int kc = threadIdx.x & 63, mg = threadIdx.x >> 6;
#pragma unroll
    for (int i = 0; i < 16; ++i) {
        int m = mg * 16 + i;
        woT[(size_t)(c0 + m) * 1024 + r0 + kc] = f2bf(tile[kc][m]);
    }
}

// ---------------- GEMM (A row-major [M][K], BT row-major [N][K]) ----------------

template<int MODE, int BN>
__global__ __launch_bounds__(256) void gemm_bt(
    const unsigned short* __restrict__ A,
    const unsigned short* __restrict__ BT,
    float* __restrict__ Cf,
    unsigned short* __restrict__ Q,
    unsigned short* __restrict__ Kq,
    unsigned short* __restrict__ V,
    int M, int N, int K)
{
    constexpr int NF = BN / 32;
    __shared__ unsigned short As[128 * 64];
    __shared__ unsigned short Bs[BN * 64];
    const int tid  = threadIdx.x;
    const int lane = tid & 63;
    const int wave = tid >> 6;
    const int wm = wave >> 1, wn = wave & 1;
    const int l15 = lane & 15, l4 = lane >> 4;
    const int row0 = blockIdx.y * 128;
    const int col0 = blockIdx.x * BN;

    f32x4 acc[4][NF];
#pragma unroll
    for (int i = 0; i < 4; ++i)
#pragma unroll
        for (int j = 0; j < NF; ++j) acc[i][j] = (f32x4){0.f, 0.f, 0.f, 0.f};

    for (int k0 = 0; k0 < K; k0 += 64) {
        __syncthreads();
#pragma unroll
        for (int it = 0; it < 4; ++it) {
            int cb = (it * 4 + wave) * 64;
            int c  = cb + lane;
            int r  = c >> 3, c8 = c & 7;
            int sc8 = c8 ^ (r & 7);
            gload_lds16(&A[(size_t)(row0 + r) * K + k0 + sc8 * 8], &As[cb * 8]);
        }
#pragma unroll
        for (int it = 0; it < NF; ++it) {
            int cb = (it * 4 + wave) * 64;
            int c  = cb + lane;
            int r  = c >> 3, c8 = c & 7;
            int sc8 = c8 ^ (r & 7);
            gload_lds16(&BT[(size_t)(col0 + r) * K + k0 + sc8 * 8], &Bs[cb * 8]);
        }
        __syncthreads();
#pragma unroll
        for (int kk = 0; kk < 2; ++kk) {
            bf16x8 af[4], bfr[NF];
#pragma unroll
            for (int m = 0; m < 4; ++m) {
                int r   = wm * 64 + m * 16 + l15;
                int blk = (kk * 4 + l4) ^ (r & 7);
                af[m] = *(const bf16x8*)&As[r * 64 + blk * 8];
            }
#pragma unroll
            for (int n = 0; n < NF; ++n) {
                int r   = wn * (BN / 2) + n * 16 + l15;
                int blk = (kk * 4 + l4) ^ (r & 7);
                bfr[n] = *(const bf16x8*)&Bs[r * 64 + blk * 8];
            }
#pragma unroll
            for (int m = 0; m < 4; ++m)
#pragma unroll
                for (int n = 0; n < NF; ++n)
                    acc[m][n] = mfma16(af[m], bfr[n], acc[m][n]);
        }
    }

#pragma unroll
    for (int m = 0; m < 4; ++m) {
#pragma unroll
        for (int n = 0; n < NF; ++n) {
#pragma unroll
            for (int r = 0; r < 4; ++r) {
                int gr = row0 + wm * 64 + m * 16 + l4 * 4 + r;
                int gc = col0 + wn * (BN / 2) + n * 16 + l15;
                float v = acc[m][n][r];
                if (MODE == 0) {
                    int s = gc >> 10, rem = gc & 1023;
                    int hh = rem >> 6, dd = rem & 63;
                    int bb = gr >> 11, ll = gr & 2047;
                    unsigned short* dst = (s == 0) ? Q : (s == 1) ? Kq : V;
                    dst[(((size_t)bb * 16 + hh) * 2048 + ll) * 64 + dd] = f2bf(v);
                } else {
                    Cf[(size_t)gr * N + gc] = v;
                }
            }
        }
    }
}

// ---------------- flash attention, swapped-QK 32x32 ----------------
// SPLIT=0: 512 blocks, 32 KV tiles, writes normalized bf16 ctx.
// SPLIT=1: 1024 blocks (2 KV halves), 16 tiles each, writes bf16 partial acc + fp32 (m,l).

template<int SPLIT>
__global__ __launch_bounds__(256) void attn_kernel(
    const unsigned short* __restrict__ qb,
    const unsigned short* __restrict__ kb,
    const unsigned short* __restrict__ vb,
    const unsigned char* __restrict__ mask,
    unsigned short* __restrict__ ctxb,        // SPLIT=0
    unsigned short* __restrict__ part,        // SPLIT=1: [half][bh][2048][64] bf16
    float* __restrict__ ml)                   // SPLIT=1: [half][bh][2048][2] f32
{
    const int lg = blockIdx.x;
    int qt, h, b, t0;
    int half = 0;
    if (SPLIT) {
        int u = ((lg & 7) << 7) | (lg >> 3);   // bijective XCD swizzle (1024 = 8*128)
        int bh = u >> 5, sub = u & 31;
        qt = sub >> 1; half = sub & 1;
        b = bh >> 4; h = bh & 15;
        t0 = half * 16;
    } else {
        int swz = ((lg & 7) << 6) | (lg >> 3);
        qt = swz & 15; h = (swz >> 4) & 15; b = swz >> 8; t0 = 0;
    }
    const int NT = SPLIT ? 16 : 32;

    const int tid  = threadIdx.x;
    const int lane = tid & 63, wave = tid >> 6;
    const int l31  = lane & 31, hi = lane >> 5;

    __shared__ unsigned short smem[16384];  // K dbuf [0,8K); Vt dbuf [8K,16K); epilogue reuse
    __shared__ int flags[32];

    const size_t hoff = ((size_t)(b * 16 + h)) * 2048 * 64;
    const unsigned short* qh = qb + hoff;
    const unsigned short* kh = kb + hoff;
    const unsigned short* vh = vb + hoff;
    const unsigned char*  mb = mask + (size_t)b * 2048;

    if (tid < 32) flags[tid] = 0;
    __syncthreads();
    {
        uint2v mv = *(const uint2v*)&mb[tid * 8];
        if (mv[0] | mv[1]) flags[tid >> 3] = 1;
    }

    const int qrow = qt * 128 + wave * 32 + l31;
    bf16x8 qf[4];
#pragma unroll
    for (int ki = 0; ki < 4; ++ki)
        qf[ki] = *(const bf16x8*)&qh[(size_t)qrow * 64 + ki * 16 + hi * 8];

    f32x16 accA = {0,0,0,0,0,0,0,0,0,0,0,0,0,0,0,0};
    f32x16 accB = {0,0,0,0,0,0,0,0,0,0,0,0,0,0,0,0};
    float m_r = -1e30f, l_r = 0.f;
    const float SC  = 0.18033688011112042f;            // 0.125 * log2(e)
    const float THR = 44.3614195558365f;               // 8 / SC  (defer-max)

    const int krow = tid >> 3, kc16 = tid & 7;
    const int vd = tid & 63, vcb = (tid >> 6) * 2;

    ushort8 kreg[2];
    unsigned short vreg[16];
    {
        const int kvb = t0 * 64;
#pragma unroll
        for (int it = 0; it < 2; ++it)
            kreg[it] = *(const ushort8*)&kh[(size_t)(kvb + krow + it * 32) * 64 + kc16 * 8];
#pragma unroll
        for (int j = 0; j < 16; ++j)
            vreg[j] = vh[(size_t)(kvb + vcb * 8 + j) * 64 + vd];
    }

    for (int t = t0; t < t0 + NT; ++t) {
        const int kv0 = t * 64;
        unsigned short* Kb = smem + (t & 1) * 4096;
        unsigned short* Vb = smem + 8192 + (t & 1) * 4096;

#pragma unroll
        for (int it = 0; it < 2; ++it) {
            int r = krow + it * 32;
            *(ushort8*)&Kb[r * 64 + ((kc16 ^ (r & 7)) * 8)] = kreg[it];
        }
        {
            union { unsigned short u[16]; ushort8 v[2]; } p;
#pragma unroll
            for (int j = 0; j < 16; ++j) p.u[j] = vreg[j];
#pragma unroll
            for (int c = 0; c < 2; ++c) {
                int cc = vcb + c;
                *(ushort8*)&Vb[vd * 64 + ((cc ^ (vd & 7)) * 8)] = p.v[c];
            }
        }
        __syncthreads();

        if (t < t0 + NT - 1) {
            const int kvn = kv0 + 64;
#pragma unroll
            for (int it = 0; it < 2; ++it)
                kreg[it] = *(const ushort8*)&kh[(size_t)(kvn + krow + it * 32) * 64 + kc16 * 8];
#pragma unroll
            for (int j = 0; j < 16; ++j)
                vreg[j] = vh[(size_t)(kvn + vcb * 8 + j) * 64 + vd];
        }

        // ---- S^T = K @ Q^T ----
        f32x16 s0 = {0,0,0,0,0,0,0,0,0,0,0,0,0,0,0,0};
        f32x16 s1 = {0,0,0,0,0,0,0,0,0,0,0,0,0,0,0,0};
        __builtin_amdgcn_s_setprio(1);
#pragma unroll
        for (int ki = 0; ki < 4; ++ki) {
            int c0 = ((ki * 2 + hi) ^ (l31 & 7)) * 8;
            bf16x8 a0 = *(const bf16x8*)&Kb[l31 * 64 + c0];
            bf16x8 a1 = *(const bf16x8*)&Kb[(32 + l31) * 64 + c0];
            s0 = mfma32(a0, qf[ki], s0);
            s1 = mfma32(a1, qf[ki], s1);
        }
        __builtin_amdgcn_s_setprio(0);

        if (flags[t]) {
#pragma unroll
            for (int r = 0; r < 16; ++r) {
                int keyl = (r & 3) + 8 * (r >> 2) + 4 * hi;
                if (mb[kv0 + keyl])      s0[r] = -1e30f;
                if (mb[kv0 + 32 + keyl]) s1[r] = -1e30f;
            }
        }

        // ---- online softmax ----
        float mx;
        {
            float a0 = fmaxf(fmaxf(s0[0], s0[1]),  fmaxf(s0[2],  s0[3]));
            float a1 = fmaxf(fmaxf(s0[4], s0[5]),  fmaxf(s0[6],  s0[7]));
            float a2 = fmaxf(fmaxf(s0[8], s0[9]),  fmaxf(s0[10], s0[11]));
            float a3 = fmaxf(fmaxf(s0[12], s0[13]), fmaxf(s0[14], s0[15]));
            float b0 = fmaxf(fmaxf(s1[0], s1[1]),  fmaxf(s1[2],  s1[3]));
            float b1 = fmaxf(fmaxf(s1[4], s1[5]),  fmaxf(s1[6],  s1[7]));
            float b2 = fmaxf(fmaxf(s1[8], s1[9]),  fmaxf(s1[10], s1[11]));
            float b3 = fmaxf(fmaxf(s1[12], s1[13]), fmaxf(s1[14], s1[15]));
            mx = fmaxf(fmaxf(fmaxf(a0, a1), fmaxf(a2, a3)),
                       fmaxf(fmaxf(b0, b1), fmaxf(b2, b3)));
        }
        mx = fmaxf(mx, __shfl_xor(mx, 32));
        if (__any(mx > m_r + THR)) {
            float mn  = fmaxf(m_r, mx);
            float scl = __builtin_amdgcn_exp2f((m_r - mn) * SC);
            m_r = mn;
            l_r *= scl;
#pragma unroll
            for (int i = 0; i < 16; ++i) { accA[i] *= scl; accB[i] *= scl; }
        }
        const float nmc = -m_r * SC;
#pragma unroll
        for (int i = 0; i < 16; ++i) {
            s0[i] = __builtin_amdgcn_exp2f(__builtin_fmaf(s0[i], SC, nmc));
            s1[i] = __builtin_amdgcn_exp2f(__builtin_fmaf(s1[i], SC, nmc));
        }
        float rs;
        {
            float a0 = (s0[0] + s0[1]) + (s0[2] + s0[3]);
            float a1 = (s0[4] + s0[5]) + (s0[6] + s0[7]);
            float a2 = (s0[8] + s0[9]) + (s0[10] + s0[11]);
            float a3 = (s0[12] + s0[13]) + (s0[14] + s0[15]);
            float b0 = (s1[0] + s1[1]) + (s1[2] + s1[3]);
            float b1 = (s1[4] + s1[5]) + (s1[6] + s1[7]);
            float b2 = (s1[8] + s1[9]) + (s1[10] + s1[11]);
            float b3 = (s1[12] + s1[13]) + (s1[14] + s1[15]);
            rs = ((a0 + a1) + (a2 + a3)) + ((b0 + b1) + (b2 + b3));
        }
        rs += __shfl_xor(rs, 32);
        l_r += rs;

        // ---- P -> bf16 B-fragments (T12) ----
        bf16x8 pf[4];
        {
            union { unsigned int u[4]; bf16x8 v; } f;
            unsigned int w0 = cvtpk_bf16(s0[0],  s0[1]),  w1 = cvtpk_bf16(s0[2],  s0[3]);
            unsigned int w2 = cvtpk_bf16(s0[4],  s0[5]),  w3 = cvtpk_bf16(s0[6],  s0[7]);
            unsigned int w4 = cvtpk_bf16(s0[8],  s0[9]),  w5 = cvtpk_bf16(s0[10], s0[11]);
            unsigned int w6 = cvtpk_bf16(s0[12], s0[13]), w7 = cvtpk_bf16(s0[14], s0[15]);
            plswap(w0, w2); plswap(w1, w3); plswap(w4, w6); plswap(w5, w7);
            f.u[0] = w0; f.u[1] = w1; f.u[2] = w2; f.u[3] = w3; pf[0] = f.v;
            f.u[0] = w4; f.u[1] = w5; f.u[2] = w6; f.u[3] = w7; pf[1] = f.v;
            unsigned int x0 = cvtpk_bf16(s1[0],  s1[1]),  x1 = cvtpk_bf16(s1[2],  s1[3]);
            unsigned int x2 = cvtpk_bf16(s1[4],  s1[5]),  x3 = cvtpk_bf16(s1[6],  s1[7]);
            unsigned int x4 = cvtpk_bf16(s1[8],  s1[9]),  x5 = cvtpk_bf16(s1[10], s1[11]);
            unsigned int x6 = cvtpk_bf16(s1[12], s1[13]), x7 = cvtpk_bf16(s1[14], s1[15]);
            plswap(x0, x2); plswap(x1, x3); plswap(x4, x6); plswap(x5, x7);
            f.u[0] = x0; f.u[1] = x1; f.u[2] = x2; f.u[3] = x3; pf[2] = f.v;
            f.u[0] = x4; f.u[1] = x5; f.u[2] = x6; f.u[3] = x7; pf[3] = f.v;
        }

        // ---- ctx^T += V^T @ P^T ----
        __builtin_amdgcn_s_setprio(1);
#pragma unroll
        for (int ks = 0; ks < 4; ++ks) {
            int c0 = ((ks * 2 + hi) ^ (l31 & 7)) * 8;
            bf16x8 vA = *(const bf16x8*)&Vb[l31 * 64 + c0];
            bf16x8 vB = *(const bf16x8*)&Vb[(32 + l31) * 64 + c0];
            accA = mfma32(vA, pf[ks], accA);
            accB = mfma32(vB, pf[ks], accB);
        }
        __builtin_amdgcn_s_setprio(0);
    }

    // ---- epilogue ----
    __syncthreads();
    const int qloc = wave * 32 + l31;
    const float inv = SPLIT ? 1.0f : (1.0f / l_r);
#pragma unroll
    for (int r = 0; r < 16; ++r) {
        int dA = (r & 3) + 8 * (r >> 2) + 4 * hi;
        smem[qloc * 64 + (dA ^ ((qloc & 7) * 8))]        = f2bf(accA[r] * inv);
        smem[qloc * 64 + ((32 + dA) ^ ((qloc & 7) * 8))] = f2bf(accB[r] * inv);
    }
    if (SPLIT && hi == 0) {
        size_t mrow = ((size_t)half * 32 + b * 16 + h) * 2048 + qt * 128 + qloc;
        *(float2*)&ml[mrow * 2] = make_float2(m_r, l_r);
    }
    __syncthreads();
    if (SPLIT) {
        const size_t prow0 = ((size_t)half * 32 + (b * 16 + h)) * 2048 + qt * 128;
#pragma unroll
        for (int it = 0; it < 4; ++it) {
            int idx = tid + it * 256;
            int q = idx >> 3, c = idx & 7;
            ushort8 vv = *(const ushort8*)&smem[q * 64 + ((c * 8) ^ ((q & 7) * 8))];
            *(ushort8*)&part[(prow0 + q) * 64 + c * 8] = vv;
        }
    } else {
#pragma unroll
        for (int it = 0; it < 4; ++it) {
            int idx = tid + it * 256;
            int q = idx >> 3, c = idx & 7;
            ushort8 vv = *(const ushort8*)&smem[q * 64 + ((c * 8) ^ ((q & 7) * 8))];
            *(ushort8*)&ctxb[((size_t)(b * 2048 + qt * 128 + q)) * 1024 + h * 64 + c * 8] = vv;
        }
    }
}

// ---------------- split-KV combine ----------------
// part: [2][32][2048][64] bf16 (unnormalized), ml: [2][32][2048][2] f32 -> ctxb bf16

__global__ void combine_kernel(const unsigned short* __restrict__ part,
                               const float* __restrict__ ml,
                               unsigned short* __restrict__ ctxb)
{
    const float SC = 0.18033688011112042f;
    int gid = blockIdx.x * 256 + threadIdx.x;          // 65536 rows * 64 d
    int row = gid >> 6, d = gid & 63;
    float p0 = bf2f(part[(size_t)row * 64 + d]);
    float p1 = bf2f(part[(size_t)(65536 + row) * 64 + d]);
    float2 a = *(const float2*)&ml[(size_t)row * 2];
    float2 c = *(const float2*)&ml[(size_t)(65536 + row) * 2];
    float m  = fmaxf(a.x, c.x);
    float w0 = __builtin_amdgcn_exp2f((a.x - m) * SC);
    float w1 = __builtin_amdgcn_exp2f((c.x - m) * SC);
    float l  = a.y * w0 + c.y * w1;
    float o  = (p0 * w0 + p1 * w1) / l;
    int bh = row >> 11, ql = row & 2047;
    int bb = bh >> 4, hh = bh & 15;
    ctxb[((size_t)(bb * 2048 + ql)) * 1024 + hh * 64 + d] = f2bf(o);
}

// ---------------- launch ----------------

extern "C" void kernel_launch(void* const* d_in, const int* in_sizes, int n_in,
                              void* d_out, int out_size, void* d_ws, size_t ws_size,
                              hipStream_t stream)
{
    const float* x  = (const float*)d_in[0];
    const float* wq = (const float*)d_in[1];
    const float* wk = (const float*)d_in[2];
    const float* wv = (const float*)d_in[3];
    const float* wo = (const float*)d_in[4];
    const unsigned char* mask = (const unsigned char*)d_in[5];
    float* out = (float*)d_out;

    char* ws = (char*)d_ws;
    unsigned short* xb   = (unsigned short*)(ws);                 //  8 MB  [4096][1024]
    unsigned short* wpT  = (unsigned short*)(ws + 8388608);       //  6 MB  [3072][1024]
    unsigned short* woT  = (unsigned short*)(ws + 14680064);      //  2 MB  [1024][1024]
    unsigned short* qb   = (unsigned short*)(ws + 16777216);      //  8 MB
    unsigned short* kb   = (unsigned short*)(ws + 25165824);      //  8 MB
    unsigned short* vb   = (unsigned short*)(ws + 33554432);      //  8 MB
    unsigned short* ctxb = (unsigned short*)(ws + 41943040);      //  8 MB  [4096][1024]
    unsigned short* part = (unsigned short*)(ws + 50331648);      // 16 MB  [2][32][2048][64] bf16
    float*          mlb  = (float*)(ws + 67108864);               //  1 MB  [2][32][2048][2] f32
    const bool split = ws_size >= (size_t)68157440;

    cast_x_kernel<<<4096, 256, 0, stream>>>(x, xb);
    pack_wqkv_t  <<<dim3(16, 48), 256, 0, stream>>>(wq, wk, wv, wpT);
    pack_wo_t    <<<dim3(16, 16), 256, 0, stream>>>(wo, woT);

    gemm_bt<0,128><<<dim3(24, 32), 256, 0, stream>>>(xb, wpT, nullptr, qb, kb, vb, 4096, 3072, 1024);

    if (split) {
        attn_kernel<1><<<1024, 256, 0, stream>>>(qb, kb, vb, mask, nullptr, part, mlb);
        combine_kernel<<<16384, 256, 0, stream>>>(part, mlb, ctxb);
    } else {
        attn_kernel<0><<<512, 256, 0, stream>>>(qb, kb, vb, mask, ctxb, nullptr, nullptr);
    }

    gemm_bt<1,64><<<dim3(16, 32), 256, 0, stream>>>(ctxb, woT, out, nullptr, nullptr, nullptr, 4096, 1024, 1024);
}

// Round 5
// 135.606 us; speedup vs baseline: 1.5654x; 1.0261x over previous
//
#include <hip/hip_runtime.h>
#include <stdint.h>

using bf16x8  = __attribute__((ext_vector_type(8))) short;           // 8 bf16 = 4 VGPR
using f32x4   = __attribute__((ext_vector_type(4))) float;
using f32x16  = __attribute__((ext_vector_type(16))) float;
using ushort8 = __attribute__((ext_vector_type(8))) unsigned short;  // 16B
using ushort4v= __attribute__((ext_vector_type(4))) unsigned short;
using uint2v  = __attribute__((ext_vector_type(2))) unsigned int;

typedef __attribute__((address_space(1))) const unsigned int* gas_ptr;
typedef __attribute__((address_space(3))) unsigned int*       las_ptr;

__device__ __forceinline__ void gload_lds16(const unsigned short* g, unsigned short* l) {
    __builtin_amdgcn_global_load_lds((gas_ptr)(const void*)g, (las_ptr)(void*)l, 16, 0, 0);
}

__device__ __forceinline__ unsigned short f2bf(float f) {
    union { float f; uint32_t u; } x; x.f = f;
    uint32_t u = x.u;
    uint32_t r = u + 0x7fffu + ((u >> 16) & 1u);   // RNE
    return (unsigned short)(r >> 16);
}
__device__ __forceinline__ float bf2f(unsigned short u) {
    union { uint32_t u; float f; } x; x.u = ((uint32_t)u) << 16;
    return x.f;
}

__device__ __forceinline__ f32x4 mfma16(bf16x8 a, bf16x8 b, f32x4 c) {
    return __builtin_amdgcn_mfma_f32_16x16x32_bf16(a, b, c, 0, 0, 0);
}
__device__ __forceinline__ f32x16 mfma32(bf16x8 a, bf16x8 b, f32x16 c) {
    return __builtin_amdgcn_mfma_f32_32x32x16_bf16(a, b, c, 0, 0, 0);
}

__device__ __forceinline__ unsigned int cvtpk_bf16(float lo, float hi) {
    unsigned int r;
    asm("v_cvt_pk_bf16_f32 %0, %1, %2" : "=v"(r) : "v"(lo), "v"(hi));
    return r;
}
__device__ __forceinline__ void plswap(unsigned int& a, unsigned int& b) {
    asm("v_permlane32_swap_b32 %0, %1" : "+v"(a), "+v"(b));
}

// ---------------- cast & pack kernels ----------------

__global__ void cast_x_kernel(const float* __restrict__ x, unsigned short* __restrict__ xb) {
    int i = blockIdx.x * 256 + threadIdx.x;
    using f32x4v = __attribute__((ext_vector_type(4))) float;
    f32x4v v = ((const f32x4v*)x)[i];
    ushort4v o;
    o[0] = f2bf(v[0]); o[1] = f2bf(v[1]); o[2] = f2bf(v[2]); o[3] = f2bf(v[3]);
    ((ushort4v*)xb)[i] = o;
}

// coalesced tiled transpose: w_s[h][k][d] -> wpT[(s*1024+h*64+d)][k]
__global__ void pack_wqkv_t(const float* __restrict__ wq, const float* __restrict__ wk,
                            const float* __restrict__ wv, unsigned short* __restrict__ wpT) {
    __shared__ float tile[64][65];
    const int mm = blockIdx.y;                 // 0..47
    const int s = mm >> 4, hh = mm & 15;
    const float* src = ((s == 0) ? wq : (s == 1) ? wk : wv) + (size_t)hh * 1024 * 64;
    const int k0 = blockIdx.x * 64;
    const int c = threadIdx.x & 63, rg = threadIdx.x >> 6;
#pragma unroll
    for (int i = 0; i < 16; ++i) {
        int r = rg * 16 + i;
        tile[r][c] = src[(size_t)(k0 + r) * 64 + c];
    }
    __syncthreads();
    unsigned short* dst = wpT + ((size_t)s * 1024 + hh * 64) * 1024 + k0;
    const int kc = threadIdx.x & 63, dg = threadIdx.x >> 6;
#pragma unroll
    for (int i = 0; i < 16; ++i) {
        int d = dg * 16 + i;
        dst[(size_t)d * 1024 + kc] = f2bf(tile[kc][d]);
    }
}

// coalesced tiled transpose: wo[k][m] -> woT[m][k]   (k = n*64+d)
__global__ void pack_wo_t(const float* __restrict__ wo, unsigned short* __restrict__ woT) {
    __shared__ float tile[64][65];
    const int r0 = blockIdx.y * 64;            // k
    const int c0 = blockIdx.x * 64;            // m
    const int c = threadIdx.x & 63, rg = threadIdx.x >> 6;
#pragma unroll
    for (int i = 0; i < 16; ++i) {
        int r = rg * 16 + i;
        tile[r][c] = wo[(size_t)(r0 + r) * 1024 + c0 + c];
    }
    __syncthreads();
    const int kc = threadIdx.x & 63, mg = threadIdx.x >> 6;
#pragma unroll
    for (int i = 0; i < 16; ++i) {
        int m = mg * 16 + i;
        woT[(size_t)(c0 + m) * 1024 + r0 + kc] = f2bf(tile[kc][m]);
    }
}

// ---------------- GEMM (A row-major [M][K], BT row-major [N][K]) ----------------

template<int MODE, int BN>
__global__ __launch_bounds__(256) void gemm_bt(
    const unsigned short* __restrict__ A,
    const unsigned short* __restrict__ BT,
    float* __restrict__ Cf,
    unsigned short* __restrict__ Q,
    unsigned short* __restrict__ Kq,
    unsigned short* __restrict__ V,
    int M, int N, int K)
{
    constexpr int NF = BN / 32;
    __shared__ unsigned short As[128 * 64];
    __shared__ unsigned short Bs[BN * 64];
    const int tid  = threadIdx.x;
    const int lane = tid & 63;
    const int wave = tid >> 6;
    const int wm = wave >> 1, wn = wave & 1;
    const int l15 = lane & 15, l4 = lane >> 4;
    const int row0 = blockIdx.y * 128;
    const int col0 = blockIdx.x * BN;

    f32x4 acc[4][NF];
#pragma unroll
    for (int i = 0; i < 4; ++i)
#pragma unroll
        for (int j = 0; j < NF; ++j) acc[i][j] = (f32x4){0.f, 0.f, 0.f, 0.f};

    for (int k0 = 0; k0 < K; k0 += 64) {
        __syncthreads();
#pragma unroll
        for (int it = 0; it < 4; ++it) {
            int cb = (it * 4 + wave) * 64;
            int c  = cb + lane;
            int r  = c >> 3, c8 = c & 7;
            int sc8 = c8 ^ (r & 7);
            gload_lds16(&A[(size_t)(row0 + r) * K + k0 + sc8 * 8], &As[cb * 8]);
        }
#pragma unroll
        for (int it = 0; it < NF; ++it) {
            int cb = (it * 4 + wave) * 64;
            int c  = cb + lane;
            int r  = c >> 3, c8 = c & 7;
            int sc8 = c8 ^ (r & 7);
            gload_lds16(&BT[(size_t)(col0 + r) * K + k0 + sc8 * 8], &Bs[cb * 8]);
        }
        __syncthreads();
#pragma unroll
        for (int kk = 0; kk < 2; ++kk) {
            bf16x8 af[4], bfr[NF];
#pragma unroll
            for (int m = 0; m < 4; ++m) {
                int r   = wm * 64 + m * 16 + l15;
                int blk = (kk * 4 + l4) ^ (r & 7);
                af[m] = *(const bf16x8*)&As[r * 64 + blk * 8];
            }
#pragma unroll
            for (int n = 0; n < NF; ++n) {
                int r   = wn * (BN / 2) + n * 16 + l15;
                int blk = (kk * 4 + l4) ^ (r & 7);
                bfr[n] = *(const bf16x8*)&Bs[r * 64 + blk * 8];
            }
#pragma unroll
            for (int m = 0; m < 4; ++m)
#pragma unroll
                for (int n = 0; n < NF; ++n)
                    acc[m][n] = mfma16(af[m], bfr[n], acc[m][n]);
        }
    }

#pragma unroll
    for (int m = 0; m < 4; ++m) {
#pragma unroll
        for (int n = 0; n < NF; ++n) {
#pragma unroll
            for (int r = 0; r < 4; ++r) {
                int gr = row0 + wm * 64 + m * 16 + l4 * 4 + r;
                int gc = col0 + wn * (BN / 2) + n * 16 + l15;
                float v = acc[m][n][r];
                if (MODE == 0) {
                    int s = gc >> 10, rem = gc & 1023;
                    int hh = rem >> 6, dd = rem & 63;
                    int bb = gr >> 11, ll = gr & 2047;
                    unsigned short* dst = (s == 0) ? Q : (s == 1) ? Kq : V;
                    dst[(((size_t)bb * 16 + hh) * 2048 + ll) * 64 + dd] = f2bf(v);
                } else {
                    Cf[(size_t)gr * N + gc] = v;
                }
            }
        }
    }
}

// ---------------- flash attention, swapped-QK 32x32, split-KV=2 ----------------
// 1024 blocks (2 KV halves x 512), 16 tiles each; writes bf16 partial acc + fp32 (m,l).

__global__ __launch_bounds__(256) void attn_kernel(
    const unsigned short* __restrict__ qb,
    const unsigned short* __restrict__ kb,
    const unsigned short* __restrict__ vb,
    const unsigned char* __restrict__ mask,
    unsigned short* __restrict__ part0,       // [32][2048][64] bf16 (half 0)
    unsigned short* __restrict__ part1,       // [32][2048][64] bf16 (half 1)
    float* __restrict__ ml)                   // [2][32][2048][2] f32
{
    const int lg = blockIdx.x;
    int u = ((lg & 7) << 7) | (lg >> 3);       // bijective XCD swizzle (1024 = 8*128)
    int bh = u >> 5, sub = u & 31;
    const int qt = sub >> 1, half = sub & 1;
    const int b = bh >> 4, h = bh & 15;
    const int t0 = half * 16;
    const int NT = 16;

    const int tid  = threadIdx.x;
    const int lane = tid & 63, wave = tid >> 6;
    const int l31  = lane & 31, hi = lane >> 5;

    __shared__ unsigned short smem[16384];  // K dbuf [0,8K); Vt dbuf [8K,16K); epilogue reuse
    __shared__ int flags[32];

    const size_t hoff = ((size_t)(b * 16 + h)) * 2048 * 64;
    const unsigned short* qh = qb + hoff;
    const unsigned short* kh = kb + hoff;
    const unsigned short* vh = vb + hoff;
    const unsigned char*  mb = mask + (size_t)b * 2048;

    if (tid < 32) flags[tid] = 0;
    __syncthreads();
    {
        uint2v mv = *(const uint2v*)&mb[tid * 8];
        if (mv[0] | mv[1]) flags[tid >> 3] = 1;
    }

    const int qrow = qt * 128 + wave * 32 + l31;
    bf16x8 qf[4];
#pragma unroll
    for (int ki = 0; ki < 4; ++ki)
        qf[ki] = *(const bf16x8*)&qh[(size_t)qrow * 64 + ki * 16 + hi * 8];

    f32x16 accA = {0,0,0,0,0,0,0,0,0,0,0,0,0,0,0,0};
    f32x16 accB = {0,0,0,0,0,0,0,0,0,0,0,0,0,0,0,0};
    float m_r = -1e30f, l_r = 0.f;
    const float SC  = 0.18033688011112042f;            // 0.125 * log2(e)
    const float THR = 44.3614195558365f;               // 8 / SC  (defer-max)

    const int krow = tid >> 3, kc16 = tid & 7;
    const int vd = tid & 63, vcb = (tid >> 6) * 2;

    ushort8 kreg[2];
    unsigned short vreg[16];
    {
        const int kvb = t0 * 64;
#pragma unroll
        for (int it = 0; it < 2; ++it)
            kreg[it] = *(const ushort8*)&kh[(size_t)(kvb + krow + it * 32) * 64 + kc16 * 8];
#pragma unroll
        for (int j = 0; j < 16; ++j)
            vreg[j] = vh[(size_t)(kvb + vcb * 8 + j) * 64 + vd];
    }

    for (int t = t0; t < t0 + NT; ++t) {
        const int kv0 = t * 64;
        unsigned short* Kb = smem + (t & 1) * 4096;
        unsigned short* Vb = smem + 8192 + (t & 1) * 4096;

#pragma unroll
        for (int it = 0; it < 2; ++it) {
            int r = krow + it * 32;
            *(ushort8*)&Kb[r * 64 + ((kc16 ^ (r & 7)) * 8)] = kreg[it];
        }
        {
            union { unsigned short u[16]; ushort8 v[2]; } p;
#pragma unroll
            for (int j = 0; j < 16; ++j) p.u[j] = vreg[j];
#pragma unroll
            for (int c = 0; c < 2; ++c) {
                int cc = vcb + c;
                *(ushort8*)&Vb[vd * 64 + ((cc ^ (vd & 7)) * 8)] = p.v[c];
            }
        }
        __syncthreads();

        if (t < t0 + NT - 1) {
            const int kvn = kv0 + 64;
#pragma unroll
            for (int it = 0; it < 2; ++it)
                kreg[it] = *(const ushort8*)&kh[(size_t)(kvn + krow + it * 32) * 64 + kc16 * 8];
#pragma unroll
            for (int j = 0; j < 16; ++j)
                vreg[j] = vh[(size_t)(kvn + vcb * 8 + j) * 64 + vd];
        }

        // ---- S^T = K @ Q^T ----
        f32x16 s0 = {0,0,0,0,0,0,0,0,0,0,0,0,0,0,0,0};
        f32x16 s1 = {0,0,0,0,0,0,0,0,0,0,0,0,0,0,0,0};
        __builtin_amdgcn_s_setprio(1);
#pragma unroll
        for (int ki = 0; ki < 4; ++ki) {
            int c0 = ((ki * 2 + hi) ^ (l31 & 7)) * 8;
            bf16x8 a0 = *(const bf16x8*)&Kb[l31 * 64 + c0];
            bf16x8 a1 = *(const bf16x8*)&Kb[(32 + l31) * 64 + c0];
            s0 = mfma32(a0, qf[ki], s0);
            s1 = mfma32(a1, qf[ki], s1);
        }
        __builtin_amdgcn_s_setprio(0);

        if (flags[t]) {
#pragma unroll
            for (int r = 0; r < 16; ++r) {
                int keyl = (r & 3) + 8 * (r >> 2) + 4 * hi;
                if (mb[kv0 + keyl])      s0[r] = -1e30f;
                if (mb[kv0 + 32 + keyl]) s1[r] = -1e30f;
            }
        }

        // ---- online softmax ----
        float mx;
        {
            float a0 = fmaxf(fmaxf(s0[0], s0[1]),  fmaxf(s0[2],  s0[3]));
            float a1 = fmaxf(fmaxf(s0[4], s0[5]),  fmaxf(s0[6],  s0[7]));
            float a2 = fmaxf(fmaxf(s0[8], s0[9]),  fmaxf(s0[10], s0[11]));
            float a3 = fmaxf(fmaxf(s0[12], s0[13]), fmaxf(s0[14], s0[15]));
            float b0 = fmaxf(fmaxf(s1[0], s1[1]),  fmaxf(s1[2],  s1[3]));
            float b1 = fmaxf(fmaxf(s1[4], s1[5]),  fmaxf(s1[6],  s1[7]));
            float b2 = fmaxf(fmaxf(s1[8], s1[9]),  fmaxf(s1[10], s1[11]));
            float b3 = fmaxf(fmaxf(s1[12], s1[13]), fmaxf(s1[14], s1[15]));
            mx = fmaxf(fmaxf(fmaxf(a0, a1), fmaxf(a2, a3)),
                       fmaxf(fmaxf(b0, b1), fmaxf(b2, b3)));
        }
        mx = fmaxf(mx, __shfl_xor(mx, 32));
        if (__any(mx > m_r + THR)) {
            float mn  = fmaxf(m_r, mx);
            float scl = __builtin_amdgcn_exp2f((m_r - mn) * SC);
            m_r = mn;
            l_r *= scl;
#pragma unroll
            for (int i = 0; i < 16; ++i) { accA[i] *= scl; accB[i] *= scl; }
        }
        const float nmc = -m_r * SC;
#pragma unroll
        for (int i = 0; i < 16; ++i) {
            s0[i] = __builtin_amdgcn_exp2f(__builtin_fmaf(s0[i], SC, nmc));
            s1[i] = __builtin_amdgcn_exp2f(__builtin_fmaf(s1[i], SC, nmc));
        }
        float rs;
        {
            float a0 = (s0[0] + s0[1]) + (s0[2] + s0[3]);
            float a1 = (s0[4] + s0[5]) + (s0[6] + s0[7]);
            float a2 = (s0[8] + s0[9]) + (s0[10] + s0[11]);
            float a3 = (s0[12] + s0[13]) + (s0[14] + s0[15]);
            float b0 = (s1[0] + s1[1]) + (s1[2] + s1[3]);
            float b1 = (s1[4] + s1[5]) + (s1[6] + s1[7]);
            float b2 = (s1[8] + s1[9]) + (s1[10] + s1[11]);
            float b3 = (s1[12] + s1[13]) + (s1[14] + s1[15]);
            rs = ((a0 + a1) + (a2 + a3)) + ((b0 + b1) + (b2 + b3));
        }
        rs += __shfl_xor(rs, 32);
        l_r += rs;

        // ---- P -> bf16 B-fragments (T12) ----
        bf16x8 pf[4];
        {
            union { unsigned int u[4]; bf16x8 v; } f;
            unsigned int w0 = cvtpk_bf16(s0[0],  s0[1]),  w1 = cvtpk_bf16(s0[2],  s0[3]);
            unsigned int w2 = cvtpk_bf16(s0[4],  s0[5]),  w3 = cvtpk_bf16(s0[6],  s0[7]);
            unsigned int w4 = cvtpk_bf16(s0[8],  s0[9]),  w5 = cvtpk_bf16(s0[10], s0[11]);
            unsigned int w6 = cvtpk_bf16(s0[12], s0[13]), w7 = cvtpk_bf16(s0[14], s0[15]);
            plswap(w0, w2); plswap(w1, w3); plswap(w4, w6); plswap(w5, w7);
            f.u[0] = w0; f.u[1] = w1; f.u[2] = w2; f.u[3] = w3; pf[0] = f.v;
            f.u[0] = w4; f.u[1] = w5; f.u[2] = w6; f.u[3] = w7; pf[1] = f.v;
            unsigned int x0 = cvtpk_bf16(s1[0],  s1[1]),  x1 = cvtpk_bf16(s1[2],  s1[3]);
            unsigned int x2 = cvtpk_bf16(s1[4],  s1[5]),  x3 = cvtpk_bf16(s1[6],  s1[7]);
            unsigned int x4 = cvtpk_bf16(s1[8],  s1[9]),  x5 = cvtpk_bf16(s1[10], s1[11]);
            unsigned int x6 = cvtpk_bf16(s1[12], s1[13]), x7 = cvtpk_bf16(s1[14], s1[15]);
            plswap(x0, x2); plswap(x1, x3); plswap(x4, x6); plswap(x5, x7);
            f.u[0] = x0; f.u[1] = x1; f.u[2] = x2; f.u[3] = x3; pf[2] = f.v;
            f.u[0] = x4; f.u[1] = x5; f.u[2] = x6; f.u[3] = x7; pf[3] = f.v;
        }

        // ---- ctx^T += V^T @ P^T ----
        __builtin_amdgcn_s_setprio(1);
#pragma unroll
        for (int ks = 0; ks < 4; ++ks) {
            int c0 = ((ks * 2 + hi) ^ (l31 & 7)) * 8;
            bf16x8 vA = *(const bf16x8*)&Vb[l31 * 64 + c0];
            bf16x8 vB = *(const bf16x8*)&Vb[(32 + l31) * 64 + c0];
            accA = mfma32(vA, pf[ks], accA);
            accB = mfma32(vB, pf[ks], accB);
        }
        __builtin_amdgcn_s_setprio(0);
    }

    // ---- epilogue: unnormalized bf16 partials + (m,l) ----
    __syncthreads();
    const int qloc = wave * 32 + l31;
#pragma unroll
    for (int r = 0; r < 16; ++r) {
        int dA = (r & 3) + 8 * (r >> 2) + 4 * hi;
        smem[qloc * 64 + (dA ^ ((qloc & 7) * 8))]        = f2bf(accA[r]);
        smem[qloc * 64 + ((32 + dA) ^ ((qloc & 7) * 8))] = f2bf(accB[r]);
    }
    if (hi == 0) {
        size_t mrow = ((size_t)half * 32 + b * 16 + h) * 2048 + qt * 128 + qloc;
        *(float2*)&ml[mrow * 2] = make_float2(m_r, l_r);
    }
    __syncthreads();
    unsigned short* pdst = half ? part1 : part0;
    const size_t prow0 = ((size_t)(b * 16 + h)) * 2048 + qt * 128;
#pragma unroll
    for (int it = 0; it < 4; ++it) {
        int idx = tid + it * 256;
        int q = idx >> 3, c = idx & 7;
        ushort8 vv = *(const ushort8*)&smem[q * 64 + ((c * 8) ^ ((q & 7) * 8))];
        *(ushort8*)&pdst[(prow0 + q) * 64 + c * 8] = vv;
    }
}

// ---------------- split-KV combine ----------------
// part0/part1: [32][2048][64] bf16 (unnormalized), ml: [2][32][2048][2] f32 -> ctxb bf16

__global__ void combine_kernel(const unsigned short* __restrict__ part0,
                               const unsigned short* __restrict__ part1,
                               const float* __restrict__ ml,
                               unsigned short* __restrict__ ctxb)
{
    const float SC = 0.18033688011112042f;
    int gid = blockIdx.x * 256 + threadIdx.x;          // 65536 rows * 8 chunks
    int row = gid >> 3, c = gid & 7;
    ushort8 v0 = *(const ushort8*)&part0[(size_t)row * 64 + c * 8];
    ushort8 v1 = *(const ushort8*)&part1[(size_t)row * 64 + c * 8];
    float2 a = *(const float2*)&ml[(size_t)row * 2];
    float2 d = *(const float2*)&ml[(size_t)(65536 + row) * 2];
    float m  = fmaxf(a.x, d.x);
    float w0 = __builtin_amdgcn_exp2f((a.x - m) * SC);
    float w1 = __builtin_amdgcn_exp2f((d.x - m) * SC);
    float li = 1.0f / (a.y * w0 + d.y * w1);
    ushort8 o;
#pragma unroll
    for (int j = 0; j < 8; ++j)
        o[j] = f2bf((bf2f(v0[j]) * w0 + bf2f(v1[j]) * w1) * li);
    int bh = row >> 11, ql = row & 2047;
    int bb = bh >> 4, hh = bh & 15;
    *(ushort8*)&ctxb[((size_t)(bb * 2048 + ql)) * 1024 + hh * 64 + c * 8] = o;
}

// ---------------- launch ----------------

extern "C" void kernel_launch(void* const* d_in, const int* in_sizes, int n_in,
                              void* d_out, int out_size, void* d_ws, size_t ws_size,
                              hipStream_t stream)
{
    const float* x  = (const float*)d_in[0];
    const float* wq = (const float*)d_in[1];
    const float* wk = (const float*)d_in[2];
    const float* wv = (const float*)d_in[3];
    const float* wo = (const float*)d_in[4];
    const unsigned char* mask = (const unsigned char*)d_in[5];
    float* out = (float*)d_out;

    char* ws = (char*)d_ws;
    unsigned short* xb   = (unsigned short*)(ws);                 //  8 MB  [4096][1024]
    unsigned short* wpT  = (unsigned short*)(ws + 8388608);       //  6 MB  [3072][1024]
    unsigned short* woT  = (unsigned short*)(ws + 14680064);      //  2 MB  [1024][1024]
    unsigned short* qb   = (unsigned short*)(ws + 16777216);      //  8 MB
    unsigned short* kb   = (unsigned short*)(ws + 25165824);      //  8 MB
    unsigned short* vb   = (unsigned short*)(ws + 33554432);      //  8 MB
    unsigned short* ctxb = (unsigned short*)(ws + 41943040);      //  8 MB  [4096][1024]
    // scratch reuse (stream-ordered, race-free):
    //   part0 overlays xb (dead after gemm<0>); part1 + ml live in d_out
    //   (only written by the final gemm<1>, which runs after combine).
    unsigned short* part0 = xb;                                   //  8 MB
    unsigned short* part1 = (unsigned short*)d_out;               //  8 MB
    float*          mlb   = (float*)((char*)d_out + 8388608);     //  1 MB

    cast_x_kernel<<<4096, 256, 0, stream>>>(x, xb);
    pack_wqkv_t  <<<dim3(16, 48), 256, 0, stream>>>(wq, wk, wv, wpT);
    pack_wo_t    <<<dim3(16, 16), 256, 0, stream>>>(wo, woT);

    gemm_bt<0,128><<<dim3(24, 32), 256, 0, stream>>>(xb, wpT, nullptr, qb, kb, vb, 4096, 3072, 1024);

    attn_kernel<<<1024, 256, 0, stream>>>(qb, kb, vb, mask, part0, part1, mlb);
    combine_kernel<<<2048, 256, 0, stream>>>(part0, part1, mlb, ctxb);

    gemm_bt<1,64><<<dim3(16, 32), 256, 0, stream>>>(ctxb, woT, out, nullptr, nullptr, nullptr, 4096, 1024, 1024);
}

// Round 6
// 133.373 us; speedup vs baseline: 1.5916x; 1.0167x over previous
//
#include <hip/hip_runtime.h>
#include <stdint.h>

using bf16x8  = __attribute__((ext_vector_type(8))) short;           // 8 bf16 = 4 VGPR
using f32x4   = __attribute__((ext_vector_type(4))) float;
using f32x16  = __attribute__((ext_vector_type(16))) float;
using ushort8 = __attribute__((ext_vector_type(8))) unsigned short;  // 16B
using ushort4v= __attribute__((ext_vector_type(4))) unsigned short;
using uint2v  = __attribute__((ext_vector_type(2))) unsigned int;

typedef __attribute__((address_space(1))) const unsigned int* gas_ptr;
typedef __attribute__((address_space(3))) unsigned int*       las_ptr;

__device__ __forceinline__ void gload_lds16(const unsigned short* g, unsigned short* l) {
    // async global->LDS, 16B/lane; LDS dest = wave-uniform base + lane*16
    __builtin_amdgcn_global_load_lds((gas_ptr)(const void*)g, (las_ptr)(void*)l, 16, 0, 0);
}

__device__ __forceinline__ unsigned short f2bf(float f) {
    union { float f; uint32_t u; } x; x.f = f;
    uint32_t u = x.u;
    uint32_t r = u + 0x7fffu + ((u >> 16) & 1u);   // RNE
    return (unsigned short)(r >> 16);
}
__device__ __forceinline__ float bf2f(unsigned short u) {
    union { uint32_t u; float f; } x; x.u = ((uint32_t)u) << 16;
    return x.f;
}

__device__ __forceinline__ f32x4 mfma16(bf16x8 a, bf16x8 b, f32x4 c) {
    return __builtin_amdgcn_mfma_f32_16x16x32_bf16(a, b, c, 0, 0, 0);
}
__device__ __forceinline__ f32x16 mfma32(bf16x8 a, bf16x8 b, f32x16 c) {
    return __builtin_amdgcn_mfma_f32_32x32x16_bf16(a, b, c, 0, 0, 0);
}

__device__ __forceinline__ unsigned int cvtpk_bf16(float lo, float hi) {
    unsigned int r;
    asm("v_cvt_pk_bf16_f32 %0, %1, %2" : "=v"(r) : "v"(lo), "v"(hi));
    return r;
}
__device__ __forceinline__ void plswap(unsigned int& a, unsigned int& b) {
    asm("v_permlane32_swap_b32 %0, %1" : "+v"(a), "+v"(b));
}

// ---------------- cast & pack kernels ----------------

__global__ void cast_x_kernel(const float* __restrict__ x, unsigned short* __restrict__ xb) {
    int i = blockIdx.x * 256 + threadIdx.x;
    using f32x4v = __attribute__((ext_vector_type(4))) float;
    f32x4v v = ((const f32x4v*)x)[i];
    ushort4v o;
    o[0] = f2bf(v[0]); o[1] = f2bf(v[1]); o[2] = f2bf(v[2]); o[3] = f2bf(v[3]);
    ((ushort4v*)xb)[i] = o;
}

// coalesced tiled transpose: w_s[h][k][d] -> wpT[(s*1024+h*64+d)][k]
__global__ void pack_wqkv_t(const float* __restrict__ wq, const float* __restrict__ wk,
                            const float* __restrict__ wv, unsigned short* __restrict__ wpT) {
    __shared__ float tile[64][65];
    const int mm = blockIdx.y;                 // 0..47
    const int s = mm >> 4, hh = mm & 15;
    const float* src = ((s == 0) ? wq : (s == 1) ? wk : wv) + (size_t)hh * 1024 * 64;
    const int k0 = blockIdx.x * 64;
    const int c = threadIdx.x & 63, rg = threadIdx.x >> 6;
#pragma unroll
    for (int i = 0; i < 16; ++i) {
        int r = rg * 16 + i;
        tile[r][c] = src[(size_t)(k0 + r) * 64 + c];
    }
    __syncthreads();
    unsigned short* dst = wpT + ((size_t)s * 1024 + hh * 64) * 1024 + k0;
    const int kc = threadIdx.x & 63, dg = threadIdx.x >> 6;
#pragma unroll
    for (int i = 0; i < 16; ++i) {
        int d = dg * 16 + i;
        dst[(size_t)d * 1024 + kc] = f2bf(tile[kc][d]);
    }
}

// coalesced tiled transpose: wo[k][m] -> woT[m][k]   (k = n*64+d)
__global__ void pack_wo_t(const float* __restrict__ wo, unsigned short* __restrict__ woT) {
    __shared__ float tile[64][65];
    const int r0 = blockIdx.y * 64;            // k
    const int c0 = blockIdx.x * 64;            // m
    const int c = threadIdx.x & 63, rg = threadIdx.x >> 6;
#pragma unroll
    for (int i = 0; i < 16; ++i) {
        int r = rg * 16 + i;
        tile[r][c] = wo[(size_t)(r0 + r) * 1024 + c0 + c];
    }
    __syncthreads();
    const int kc = threadIdx.x & 63, mg = threadIdx.x >> 6;
#pragma unroll
    for (int i = 0; i < 16; ++i) {
        int m = mg * 16 + i;
        woT[(size_t)(c0 + m) * 1024 + r0 + kc] = f2bf(tile[kc][m]);
    }
}

// bf16 transpose: vb [bh][l=2048][d=64] -> vtb [bh][d=64][l=2048]
__global__ void vt_kernel(const unsigned short* __restrict__ vb, unsigned short* __restrict__ vtb) {
    __shared__ unsigned short tile[64][72];
    const int bh = blockIdx.y;
    const int l0 = blockIdx.x * 64;
    const unsigned short* src = vb + (size_t)bh * 131072;
    unsigned short* dst = vtb + (size_t)bh * 131072;
    const int c8 = threadIdx.x & 7, r2 = threadIdx.x >> 3;   // r2 in 0..31
#pragma unroll
    for (int it = 0; it < 2; ++it) {
        int r = r2 + it * 32;
        ushort8 v = *(const ushort8*)&src[(size_t)(l0 + r) * 64 + c8 * 8];
        *(ushort8*)&tile[r][c8 * 8] = v;
    }
    __syncthreads();
#pragma unroll
    for (int it = 0; it < 2; ++it) {
        int d = r2 + it * 32;
        ushort8 o;
#pragma unroll
        for (int j = 0; j < 8; ++j) o[j] = tile[c8 * 8 + j][d];
        *(ushort8*)&dst[(size_t)d * 2048 + l0 + c8 * 8] = o;
    }
}

// ---------------- GEMM (A row-major [M][K], BT row-major [N][K]) ----------------

template<int MODE, int BN>
__global__ __launch_bounds__(256) void gemm_bt(
    const unsigned short* __restrict__ A,
    const unsigned short* __restrict__ BT,
    float* __restrict__ Cf,
    unsigned short* __restrict__ Q,
    unsigned short* __restrict__ Kq,
    unsigned short* __restrict__ V,
    int M, int N, int K)
{
    constexpr int NF = BN / 32;
    __shared__ unsigned short As[128 * 64];
    __shared__ unsigned short Bs[BN * 64];
    const int tid  = threadIdx.x;
    const int lane = tid & 63;
    const int wave = tid >> 6;
    const int wm = wave >> 1, wn = wave & 1;
    const int l15 = lane & 15, l4 = lane >> 4;
    const int row0 = blockIdx.y * 128;
    const int col0 = blockIdx.x * BN;

    f32x4 acc[4][NF];
#pragma unroll
    for (int i = 0; i < 4; ++i)
#pragma unroll
        for (int j = 0; j < NF; ++j) acc[i][j] = (f32x4){0.f, 0.f, 0.f, 0.f};

    for (int k0 = 0; k0 < K; k0 += 64) {
        __syncthreads();
#pragma unroll
        for (int it = 0; it < 4; ++it) {
            int cb = (it * 4 + wave) * 64;
            int c  = cb + lane;
            int r  = c >> 3, c8 = c & 7;
            int sc8 = c8 ^ (r & 7);
            gload_lds16(&A[(size_t)(row0 + r) * K + k0 + sc8 * 8], &As[cb * 8]);
        }
#pragma unroll
        for (int it = 0; it < NF; ++it) {
            int cb = (it * 4 + wave) * 64;
            int c  = cb + lane;
            int r  = c >> 3, c8 = c & 7;
            int sc8 = c8 ^ (r & 7);
            gload_lds16(&BT[(size_t)(col0 + r) * K + k0 + sc8 * 8], &Bs[cb * 8]);
        }
        __syncthreads();
#pragma unroll
        for (int kk = 0; kk < 2; ++kk) {
            bf16x8 af[4], bfr[NF];
#pragma unroll
            for (int m = 0; m < 4; ++m) {
                int r   = wm * 64 + m * 16 + l15;
                int blk = (kk * 4 + l4) ^ (r & 7);
                af[m] = *(const bf16x8*)&As[r * 64 + blk * 8];
            }
#pragma unroll
            for (int n = 0; n < NF; ++n) {
                int r   = wn * (BN / 2) + n * 16 + l15;
                int blk = (kk * 4 + l4) ^ (r & 7);
                bfr[n] = *(const bf16x8*)&Bs[r * 64 + blk * 8];
            }
#pragma unroll
            for (int m = 0; m < 4; ++m)
#pragma unroll
                for (int n = 0; n < NF; ++n)
                    acc[m][n] = mfma16(af[m], bfr[n], acc[m][n]);
        }
    }

#pragma unroll
    for (int m = 0; m < 4; ++m) {
#pragma unroll
        for (int n = 0; n < NF; ++n) {
#pragma unroll
            for (int r = 0; r < 4; ++r) {
                int gr = row0 + wm * 64 + m * 16 + l4 * 4 + r;
                int gc = col0 + wn * (BN / 2) + n * 16 + l15;
                float v = acc[m][n][r];
                if (MODE == 0) {
                    int s = gc >> 10, rem = gc & 1023;
                    int hh = rem >> 6, dd = rem & 63;
                    int bb = gr >> 11, ll = gr & 2047;
                    unsigned short* dst = (s == 0) ? Q : (s == 1) ? Kq : V;
                    dst[(((size_t)bb * 16 + hh) * 2048 + ll) * 64 + dd] = f2bf(v);
                } else {
                    Cf[(size_t)gr * N + gc] = v;
                }
            }
        }
    }
}

// ---------------- flash attention, swapped-QK 32x32, split-KV=2, gload_lds staging ----------------
// 1024 blocks (2 KV halves x 512), 16 tiles each; low-reg variant targeting 4 waves/SIMD.

__global__ __launch_bounds__(256, 4) void attn_kernel(
    const unsigned short* __restrict__ qb,
    const unsigned short* __restrict__ kb,
    const unsigned short* __restrict__ vtb,   // [bh][64][2048] bf16 (V transposed)
    const unsigned char* __restrict__ mask,
    unsigned short* __restrict__ part0,       // [32][2048][64] bf16 (half 0)
    unsigned short* __restrict__ part1,       // [32][2048][64] bf16 (half 1)
    float* __restrict__ ml)                   // [2][32][2048][2] f32
{
    const int lg = blockIdx.x;
    int u = ((lg & 7) << 7) | (lg >> 3);       // bijective XCD swizzle (1024 = 8*128)
    int bh = u >> 5, sub = u & 31;
    const int qt = sub >> 1, half = sub & 1;
    const int b = bh >> 4, h = bh & 15;
    const int t0 = half * 16;
    const int NT = 16;

    const int tid  = threadIdx.x;
    const int lane = tid & 63, wave = tid >> 6;
    const int l31  = lane & 31, hi = lane >> 5;

    __shared__ unsigned short smem[16384];  // K dbuf [0,8K); Vt dbuf [8K,16K) ushorts
    __shared__ int flags[32];

    const size_t hoff = (size_t)bh * 131072;
    const unsigned short* qh  = qb  + hoff;
    const unsigned short* kh  = kb  + hoff;
    const unsigned short* vth = vtb + hoff;
    const unsigned char*  mb  = mask + (size_t)b * 2048;

    if (tid < 32) flags[tid] = 0;
    __syncthreads();
    {
        uint2v mv = *(const uint2v*)&mb[tid * 8];
        if (mv[0] | mv[1]) flags[tid >> 3] = 1;
    }

    const int qrow = qt * 128 + wave * 32 + l31;
    bf16x8 qf[4];
#pragma unroll
    for (int ki = 0; ki < 4; ++ki)
        qf[ki] = *(const bf16x8*)&qh[(size_t)qrow * 64 + ki * 16 + hi * 8];

    f32x16 accA = {0,0,0,0,0,0,0,0,0,0,0,0,0,0,0,0};
    f32x16 accB = {0,0,0,0,0,0,0,0,0,0,0,0,0,0,0,0};
    float m_r = -1e30f, l_r = 0.f;
    const float SC  = 0.18033688011112042f;            // 0.125 * log2(e)
    const float THR = 44.3614195558365f;               // 8 / SC  (defer-max)

    // async stage via global_load_lds: 512 chunks (8 ushorts) per tile per matrix.
    // LDS linear; source pre-swizzled so swizzled READ yields logical chunk (rule #21).
#define STAGE(KB, VB, KV0) do {                                                          \
        _Pragma("unroll")                                                                \
        for (int it_ = 0; it_ < 2; ++it_) {                                              \
            int c_ = it_ * 256 + tid;                                                    \
            int r_ = c_ >> 3, c8_ = c_ & 7;                                              \
            int sc8_ = c8_ ^ (r_ & 7);                                                   \
            gload_lds16(&kh[(size_t)((KV0) + r_) * 64 + sc8_ * 8],                       \
                        &(KB)[(it_ * 256 + wave * 64) * 8]);                             \
            gload_lds16(&vth[(size_t)r_ * 2048 + (KV0) + sc8_ * 8],                      \
                        &(VB)[(it_ * 256 + wave * 64) * 8]);                             \
        }                                                                                \
    } while (0)

    STAGE(smem, smem + 8192, t0 * 64);         // prologue -> buffer parity 0

    for (int t = t0; t < t0 + NT; ++t) {
        const int kv0 = t * 64;
        unsigned short* Kb = smem + ((t - t0) & 1) * 4096;
        unsigned short* Vb = smem + 8192 + ((t - t0) & 1) * 4096;
        __syncthreads();                       // drains vmcnt -> tile t staged; prev readers done
        if (t + 1 < t0 + NT) {
            unsigned short* Kn = smem + ((t + 1 - t0) & 1) * 4096;
            unsigned short* Vn = smem + 8192 + ((t + 1 - t0) & 1) * 4096;
            STAGE(Kn, Vn, kv0 + 64);           // prefetch next tile under compute
        }

        // ---- S^T = K @ Q^T ----
        f32x16 s0 = {0,0,0,0,0,0,0,0,0,0,0,0,0,0,0,0};
        f32x16 s1 = {0,0,0,0,0,0,0,0,0,0,0,0,0,0,0,0};
        __builtin_amdgcn_s_setprio(1);
#pragma unroll
        for (int ki = 0; ki < 4; ++ki) {
            int c0 = ((ki * 2 + hi) ^ (l31 & 7)) * 8;
            bf16x8 a0 = *(const bf16x8*)&Kb[l31 * 64 + c0];
            bf16x8 a1 = *(const bf16x8*)&Kb[(32 + l31) * 64 + c0];
            s0 = mfma32(a0, qf[ki], s0);
            s1 = mfma32(a1, qf[ki], s1);
        }
        __builtin_amdgcn_s_setprio(0);

        if (flags[t]) {
#pragma unroll
            for (int r = 0; r < 16; ++r) {
                int keyl = (r & 3) + 8 * (r >> 2) + 4 * hi;
                if (mb[kv0 + keyl])      s0[r] = -1e30f;
                if (mb[kv0 + 32 + keyl]) s1[r] = -1e30f;
            }
        }

        // ---- online softmax ----
        float mx;
        {
            float a0 = fmaxf(fmaxf(s0[0], s0[1]),  fmaxf(s0[2],  s0[3]));
            float a1 = fmaxf(fmaxf(s0[4], s0[5]),  fmaxf(s0[6],  s0[7]));
            float a2 = fmaxf(fmaxf(s0[8], s0[9]),  fmaxf(s0[10], s0[11]));
            float a3 = fmaxf(fmaxf(s0[12], s0[13]), fmaxf(s0[14], s0[15]));
            float b0 = fmaxf(fmaxf(s1[0], s1[1]),  fmaxf(s1[2],  s1[3]));
            float b1 = fmaxf(fmaxf(s1[4], s1[5]),  fmaxf(s1[6],  s1[7]));
            float b2 = fmaxf(fmaxf(s1[8], s1[9]),  fmaxf(s1[10], s1[11]));
            float b3 = fmaxf(fmaxf(s1[12], s1[13]), fmaxf(s1[14], s1[15]));
            mx = fmaxf(fmaxf(fmaxf(a0, a1), fmaxf(a2, a3)),
                       fmaxf(fmaxf(b0, b1), fmaxf(b2, b3)));
        }
        mx = fmaxf(mx, __shfl_xor(mx, 32));
        if (__any(mx > m_r + THR)) {
            float mn  = fmaxf(m_r, mx);
            float scl = __builtin_amdgcn_exp2f((m_r - mn) * SC);
            m_r = mn;
            l_r *= scl;
#pragma unroll
            for (int i = 0; i < 16; ++i) { accA[i] *= scl; accB[i] *= scl; }
        }
        const float nmc = -m_r * SC;
#pragma unroll
        for (int i = 0; i < 16; ++i) {
            s0[i] = __builtin_amdgcn_exp2f(__builtin_fmaf(s0[i], SC, nmc));
            s1[i] = __builtin_amdgcn_exp2f(__builtin_fmaf(s1[i], SC, nmc));
        }
        float rs;
        {
            float a0 = (s0[0] + s0[1]) + (s0[2] + s0[3]);
            float a1 = (s0[4] + s0[5]) + (s0[6] + s0[7]);
            float a2 = (s0[8] + s0[9]) + (s0[10] + s0[11]);
            float a3 = (s0[12] + s0[13]) + (s0[14] + s0[15]);
            float b0 = (s1[0] + s1[1]) + (s1[2] + s1[3]);
            float b1 = (s1[4] + s1[5]) + (s1[6] + s1[7]);
            float b2 = (s1[8] + s1[9]) + (s1[10] + s1[11]);
            float b3 = (s1[12] + s1[13]) + (s1[14] + s1[15]);
            rs = ((a0 + a1) + (a2 + a3)) + ((b0 + b1) + (b2 + b3));
        }
        rs += __shfl_xor(rs, 32);
        l_r += rs;

        // ---- P -> bf16 B-fragments (T12) ----
        bf16x8 pf[4];
        {
            union { unsigned int u[4]; bf16x8 v; } f;
            unsigned int w0 = cvtpk_bf16(s0[0],  s0[1]),  w1 = cvtpk_bf16(s0[2],  s0[3]);
            unsigned int w2 = cvtpk_bf16(s0[4],  s0[5]),  w3 = cvtpk_bf16(s0[6],  s0[7]);
            unsigned int w4 = cvtpk_bf16(s0[8],  s0[9]),  w5 = cvtpk_bf16(s0[10], s0[11]);
            unsigned int w6 = cvtpk_bf16(s0[12], s0[13]), w7 = cvtpk_bf16(s0[14], s0[15]);
            plswap(w0, w2); plswap(w1, w3); plswap(w4, w6); plswap(w5, w7);
            f.u[0] = w0; f.u[1] = w1; f.u[2] = w2; f.u[3] = w3; pf[0] = f.v;
            f.u[0] = w4; f.u[1] = w5; f.u[2] = w6; f.u[3] = w7; pf[1] = f.v;
            unsigned int x0 = cvtpk_bf16(s1[0],  s1[1]),  x1 = cvtpk_bf16(s1[2],  s1[3]);
            unsigned int x2 = cvtpk_bf16(s1[4],  s1[5]),  x3 = cvtpk_bf16(s1[6],  s1[7]);
            unsigned int x4 = cvtpk_bf16(s1[8],  s1[9]),  x5 = cvtpk_bf16(s1[10], s1[11]);
            unsigned int x6 = cvtpk_bf16(s1[12], s1[13]), x7 = cvtpk_bf16(s1[14], s1[15]);
            plswap(x0, x2); plswap(x1, x3); plswap(x4, x6); plswap(x5, x7);
            f.u[0] = x0; f.u[1] = x1; f.u[2] = x2; f.u[3] = x3; pf[2] = f.v;
            f.u[0] = x4; f.u[1] = x5; f.u[2] = x6; f.u[3] = x7; pf[3] = f.v;
        }

        // ---- ctx^T += V^T @ P^T ----
        __builtin_amdgcn_s_setprio(1);
#pragma unroll
        for (int ks = 0; ks < 4; ++ks) {
            int c0 = ((ks * 2 + hi) ^ (l31 & 7)) * 8;
            bf16x8 vA = *(const bf16x8*)&Vb[l31 * 64 + c0];
            bf16x8 vB = *(const bf16x8*)&Vb[(32 + l31) * 64 + c0];
            accA = mfma32(vA, pf[ks], accA);
            accB = mfma32(vB, pf[ks], accB);
        }
        __builtin_amdgcn_s_setprio(0);
    }
#undef STAGE

    // ---- epilogue: unnormalized bf16 partials + (m,l) ----
    __syncthreads();
    const int qloc = wave * 32 + l31;
#pragma unroll
    for (int r = 0; r < 16; ++r) {
        int dA = (r & 3) + 8 * (r >> 2) + 4 * hi;
        smem[qloc * 64 + (dA ^ ((qloc & 7) * 8))]        = f2bf(accA[r]);
        smem[qloc * 64 + ((32 + dA) ^ ((qloc & 7) * 8))] = f2bf(accB[r]);
    }
    if (hi == 0) {
        size_t mrow = ((size_t)half * 32 + bh) * 2048 + qt * 128 + qloc;
        *(float2*)&ml[mrow * 2] = make_float2(m_r, l_r);
    }
    __syncthreads();
    unsigned short* pdst = half ? part1 : part0;
    const size_t prow0 = (size_t)bh * 2048 + qt * 128;
#pragma unroll
    for (int it = 0; it < 4; ++it) {
        int idx = tid + it * 256;
        int q = idx >> 3, c = idx & 7;
        ushort8 vv = *(const ushort8*)&smem[q * 64 + ((c * 8) ^ ((q & 7) * 8))];
        *(ushort8*)&pdst[(prow0 + q) * 64 + c * 8] = vv;
    }
}

// ---------------- split-KV combine ----------------

__global__ void combine_kernel(const unsigned short* __restrict__ part0,
                               const unsigned short* __restrict__ part1,
                               const float* __restrict__ ml,
                               unsigned short* __restrict__ ctxb)
{
    const float SC = 0.18033688011112042f;
    int gid = blockIdx.x * 256 + threadIdx.x;          // 65536 rows * 8 chunks
    int row = gid >> 3, c = gid & 7;
    ushort8 v0 = *(const ushort8*)&part0[(size_t)row * 64 + c * 8];
    ushort8 v1 = *(const ushort8*)&part1[(size_t)row * 64 + c * 8];
    float2 a = *(const float2*)&ml[(size_t)row * 2];
    float2 d = *(const float2*)&ml[(size_t)(65536 + row) * 2];
    float m  = fmaxf(a.x, d.x);
    float w0 = __builtin_amdgcn_exp2f((a.x - m) * SC);
    float w1 = __builtin_amdgcn_exp2f((d.x - m) * SC);
    float li = 1.0f / (a.y * w0 + d.y * w1);
    ushort8 o;
#pragma unroll
    for (int j = 0; j < 8; ++j)
        o[j] = f2bf((bf2f(v0[j]) * w0 + bf2f(v1[j]) * w1) * li);
    int bh = row >> 11, ql = row & 2047;
    int bb = bh >> 4, hh = bh & 15;
    *(ushort8*)&ctxb[((size_t)(bb * 2048 + ql)) * 1024 + hh * 64 + c * 8] = o;
}

// ---------------- launch ----------------

extern "C" void kernel_launch(void* const* d_in, const int* in_sizes, int n_in,
                              void* d_out, int out_size, void* d_ws, size_t ws_size,
                              hipStream_t stream)
{
    const float* x  = (const float*)d_in[0];
    const float* wq = (const float*)d_in[1];
    const float* wk = (const float*)d_in[2];
    const float* wv = (const float*)d_in[3];
    const float* wo = (const float*)d_in[4];
    const unsigned char* mask = (const unsigned char*)d_in[5];
    float* out = (float*)d_out;

    char* ws = (char*)d_ws;
    unsigned short* xb   = (unsigned short*)(ws);                 //  8 MB  [4096][1024]
    unsigned short* wpT  = (unsigned short*)(ws + 8388608);       //  6 MB  [3072][1024]
    unsigned short* woT  = (unsigned short*)(ws + 14680064);      //  2 MB  [1024][1024]
    unsigned short* qb   = (unsigned short*)(ws + 16777216);      //  8 MB
    unsigned short* kb   = (unsigned short*)(ws + 25165824);      //  8 MB
    unsigned short* vb   = (unsigned short*)(ws + 33554432);      //  8 MB
    unsigned short* ctxb = (unsigned short*)(ws + 41943040);      //  8 MB  [4096][1024]
    // scratch reuse (stream-ordered, race-free):
    //   vtb overlays xb (dead after gemm<0>); ml overlays wpT (dead after gemm<0>);
    //   part0/part1 live in d_out (16 MB), overwritten by the final gemm<1>.
    unsigned short* vtb   = xb;                                   //  8 MB  [32][64][2048]
    unsigned short* part0 = (unsigned short*)d_out;               //  8 MB
    unsigned short* part1 = (unsigned short*)d_out + 4194304;     //  8 MB
    float*          mlb   = (float*)wpT;                          //  1 MB

    cast_x_kernel<<<4096, 256, 0, stream>>>(x, xb);
    pack_wqkv_t  <<<dim3(16, 48), 256, 0, stream>>>(wq, wk, wv, wpT);
    pack_wo_t    <<<dim3(16, 16), 256, 0, stream>>>(wo, woT);

    gemm_bt<0,128><<<dim3(24, 32), 256, 0, stream>>>(xb, wpT, nullptr, qb, kb, vb, 4096, 3072, 1024);

    vt_kernel<<<dim3(32, 32), 256, 0, stream>>>(vb, vtb);
    attn_kernel<<<1024, 256, 0, stream>>>(qb, kb, vtb, mask, part0, part1, mlb);
    combine_kernel<<<2048, 256, 0, stream>>>(part0, part1, mlb, ctxb);

    gemm_bt<1,64><<<dim3(16, 32), 256, 0, stream>>>(ctxb, woT, out, nullptr, nullptr, nullptr, 4096, 1024, 1024);
}

// Round 7
// 128.257 us; speedup vs baseline: 1.6551x; 1.0399x over previous
//
#include <hip/hip_runtime.h>
#include <stdint.h>

using bf16x8  = __attribute__((ext_vector_type(8))) short;           // 8 bf16 = 4 VGPR
using f32x4   = __attribute__((ext_vector_type(4))) float;
using f32x16  = __attribute__((ext_vector_type(16))) float;
using ushort8 = __attribute__((ext_vector_type(8))) unsigned short;  // 16B
using ushort4v= __attribute__((ext_vector_type(4))) unsigned short;
using uint2v  = __attribute__((ext_vector_type(2))) unsigned int;

typedef __attribute__((address_space(1))) const unsigned int* gas_ptr;
typedef __attribute__((address_space(3))) unsigned int*       las_ptr;

__device__ __forceinline__ void gload_lds16(const unsigned short* g, unsigned short* l) {
    // async global->LDS, 16B/lane; LDS dest = wave-uniform base + lane*16
    __builtin_amdgcn_global_load_lds((gas_ptr)(const void*)g, (las_ptr)(void*)l, 16, 0, 0);
}

__device__ __forceinline__ unsigned short f2bf(float f) {
    union { float f; uint32_t u; } x; x.f = f;
    uint32_t u = x.u;
    uint32_t r = u + 0x7fffu + ((u >> 16) & 1u);   // RNE
    return (unsigned short)(r >> 16);
}
__device__ __forceinline__ float bf2f(unsigned short u) {
    union { uint32_t u; float f; } x; x.u = ((uint32_t)u) << 16;
    return x.f;
}

__device__ __forceinline__ f32x4 mfma16(bf16x8 a, bf16x8 b, f32x4 c) {
    return __builtin_amdgcn_mfma_f32_16x16x32_bf16(a, b, c, 0, 0, 0);
}
__device__ __forceinline__ f32x16 mfma32(bf16x8 a, bf16x8 b, f32x16 c) {
    return __builtin_amdgcn_mfma_f32_32x32x16_bf16(a, b, c, 0, 0, 0);
}

__device__ __forceinline__ unsigned int cvtpk_bf16(float lo, float hi) {
    unsigned int r;
    asm("v_cvt_pk_bf16_f32 %0, %1, %2" : "=v"(r) : "v"(lo), "v"(hi));
    return r;
}
__device__ __forceinline__ void plswap(unsigned int& a, unsigned int& b) {
    asm("v_permlane32_swap_b32 %0, %1" : "+v"(a), "+v"(b));
}
__device__ __forceinline__ float m3(float a, float b, float c) {   // fuses to v_max3_f32
    return fmaxf(fmaxf(a, b), c);
}

// ---------------- cast & pack kernels ----------------

__global__ void cast_x_kernel(const float* __restrict__ x, unsigned short* __restrict__ xb) {
    int i = blockIdx.x * 256 + threadIdx.x;
    using f32x4v = __attribute__((ext_vector_type(4))) float;
    f32x4v v = ((const f32x4v*)x)[i];
    ushort4v o;
    o[0] = f2bf(v[0]); o[1] = f2bf(v[1]); o[2] = f2bf(v[2]); o[3] = f2bf(v[3]);
    ((ushort4v*)xb)[i] = o;
}

// coalesced tiled transpose: w_s[h][k][d] -> wpT[(s*1024+h*64+d)][k]
__global__ void pack_wqkv_t(const float* __restrict__ wq, const float* __restrict__ wk,
                            const float* __restrict__ wv, unsigned short* __restrict__ wpT) {
    __shared__ float tile[64][65];
    const int mm = blockIdx.y;                 // 0..47
    const int s = mm >> 4, hh = mm & 15;
    const float* src = ((s == 0) ? wq : (s == 1) ? wk : wv) + (size_t)hh * 1024 * 64;
    const int k0 = blockIdx.x * 64;
    const int c = threadIdx.x & 63, rg = threadIdx.x >> 6;
#pragma unroll
    for (int i = 0; i < 16; ++i) {
        int r = rg * 16 + i;
        tile[r][c] = src[(size_t)(k0 + r) * 64 + c];
    }
    __syncthreads();
    unsigned short* dst = wpT + ((size_t)s * 1024 + hh * 64) * 1024 + k0;
    const int kc = threadIdx.x & 63, dg = threadIdx.x >> 6;
#pragma unroll
    for (int i = 0; i < 16; ++i) {
        int d = dg * 16 + i;
        dst[(size_t)d * 1024 + kc] = f2bf(tile[kc][d]);
    }
}

// coalesced tiled transpose: wo[k][m] -> woT[m][k]   (k = n*64+d)
__global__ void pack_wo_t(const float* __restrict__ wo, unsigned short* __restrict__ woT) {
    __shared__ float tile[64][65];
    const int r0 = blockIdx.y * 64;            // k
    const int c0 = blockIdx.x * 64;            // m
    const int c = threadIdx.x & 63, rg = threadIdx.x >> 6;
#pragma unroll
    for (int i = 0; i < 16; ++i) {
        int r = rg * 16 + i;
        tile[r][c] = wo[(size_t)(r0 + r) * 1024 + c0 + c];
    }
    __syncthreads();
    const int kc = threadIdx.x & 63, mg = threadIdx.x >> 6;
#pragma unroll
    for (int i = 0; i < 16; ++i) {
        int m = mg * 16 + i;
        woT[(size_t)(c0 + m) * 1024 + r0 + kc] = f2bf(tile[kc][m]);
    }
}

// ---------------- GEMM (A row-major [M][K], BT row-major [N][K]) ----------------
// MODE 0: scatter Q/K into [bh][l][64] and V TRANSPOSED into [bh][64][2048].
// MODE 1: fp32 C row-major.

template<int MODE, int BN>
__global__ __launch_bounds__(256) void gemm_bt(
    const unsigned short* __restrict__ A,
    const unsigned short* __restrict__ BT,
    float* __restrict__ Cf,
    unsigned short* __restrict__ Q,
    unsigned short* __restrict__ Kq,
    unsigned short* __restrict__ V,
    int M, int N, int K)
{
    constexpr int NF = BN / 32;
    __shared__ unsigned short As[128 * 64];
    __shared__ unsigned short Bs[BN * 64];
    const int tid  = threadIdx.x;
    const int lane = tid & 63;
    const int wave = tid >> 6;
    const int wm = wave >> 1, wn = wave & 1;
    const int l15 = lane & 15, l4 = lane >> 4;
    const int row0 = blockIdx.y * 128;
    const int col0 = blockIdx.x * BN;

    f32x4 acc[4][NF];
#pragma unroll
    for (int i = 0; i < 4; ++i)
#pragma unroll
        for (int j = 0; j < NF; ++j) acc[i][j] = (f32x4){0.f, 0.f, 0.f, 0.f};

    for (int k0 = 0; k0 < K; k0 += 64) {
        __syncthreads();
#pragma unroll
        for (int it = 0; it < 4; ++it) {
            int cb = (it * 4 + wave) * 64;
            int c  = cb + lane;
            int r  = c >> 3, c8 = c & 7;
            int sc8 = c8 ^ (r & 7);
            gload_lds16(&A[(size_t)(row0 + r) * K + k0 + sc8 * 8], &As[cb * 8]);
        }
#pragma unroll
        for (int it = 0; it < NF; ++it) {
            int cb = (it * 4 + wave) * 64;
            int c  = cb + lane;
            int r  = c >> 3, c8 = c & 7;
            int sc8 = c8 ^ (r & 7);
            gload_lds16(&BT[(size_t)(col0 + r) * K + k0 + sc8 * 8], &Bs[cb * 8]);
        }
        __syncthreads();
#pragma unroll
        for (int kk = 0; kk < 2; ++kk) {
            bf16x8 af[4], bfr[NF];
#pragma unroll
            for (int m = 0; m < 4; ++m) {
                int r   = wm * 64 + m * 16 + l15;
                int blk = (kk * 4 + l4) ^ (r & 7);
                af[m] = *(const bf16x8*)&As[r * 64 + blk * 8];
            }
#pragma unroll
            for (int n = 0; n < NF; ++n) {
                int r   = wn * (BN / 2) + n * 16 + l15;
                int blk = (kk * 4 + l4) ^ (r & 7);
                bfr[n] = *(const bf16x8*)&Bs[r * 64 + blk * 8];
            }
#pragma unroll
            for (int m = 0; m < 4; ++m)
#pragma unroll
                for (int n = 0; n < NF; ++n)
                    acc[m][n] = mfma16(af[m], bfr[n], acc[m][n]);
        }
    }

#pragma unroll
    for (int m = 0; m < 4; ++m) {
        int gr0 = row0 + wm * 64 + m * 16 + l4 * 4;
#pragma unroll
        for (int n = 0; n < NF; ++n) {
            int gc = col0 + wn * (BN / 2) + n * 16 + l15;
            if (MODE == 0) {
                int s = gc >> 10, rem = gc & 1023;
                int hh = rem >> 6, dd = rem & 63;
                int bb = gr0 >> 11, ll = gr0 & 2047;
                if (s == 2) {
                    // V transposed: [bh][d][2048], 4 consecutive l -> 8B store
                    ushort4v o;
#pragma unroll
                    for (int r = 0; r < 4; ++r) o[r] = f2bf(acc[m][n][r]);
                    *(ushort4v*)&V[(((size_t)bb * 16 + hh) * 64 + dd) * 2048 + ll] = o;
                } else {
                    unsigned short* dst = (s == 0) ? Q : Kq;
#pragma unroll
                    for (int r = 0; r < 4; ++r)
                        dst[(((size_t)bb * 16 + hh) * 2048 + ll + r) * 64 + dd] = f2bf(acc[m][n][r]);
                }
            } else {
#pragma unroll
                for (int r = 0; r < 4; ++r)
                    Cf[(size_t)(gr0 + r) * N + gc] = acc[m][n][r];
            }
        }
    }
}

// ---------------- flash attention, swapped-QK 32x32, split-KV=2, gload_lds staging ----------------
// 1024 blocks (2 KV halves x 512), 16 tiles each.
// VALU diet: persistent-zero mfma C, max3 tree, row-sum via ones-MFMA (accL).

__global__ __launch_bounds__(256, 4) void attn_kernel(
    const unsigned short* __restrict__ qb,
    const unsigned short* __restrict__ kb,
    const unsigned short* __restrict__ vtb,   // [bh][64][2048] bf16 (V transposed)
    const unsigned char* __restrict__ mask,
    unsigned short* __restrict__ part0,       // [32][2048][64] bf16 (half 0)
    unsigned short* __restrict__ part1,       // [32][2048][64] bf16 (half 1)
    float* __restrict__ ml)                   // [2][32][2048][2] f32
{
    const int lg = blockIdx.x;
    int u = ((lg & 7) << 7) | (lg >> 3);       // bijective XCD swizzle (1024 = 8*128)
    int bh = u >> 5, sub = u & 31;
    const int qt = sub >> 1, half = sub & 1;
    const int b = bh >> 4;
    const int t0 = half * 16;
    const int NT = 16;

    const int tid  = threadIdx.x;
    const int lane = tid & 63, wave = tid >> 6;
    const int l31  = lane & 31, hi = lane >> 5;

    __shared__ unsigned short smem[16384];  // K dbuf [0,8K); Vt dbuf [8K,16K) ushorts
    __shared__ int flags[32];

    const size_t hoff = (size_t)bh * 131072;
    const unsigned short* qh  = qb  + hoff;
    const unsigned short* kh  = kb  + hoff;
    const unsigned short* vth = vtb + hoff;
    const unsigned char*  mb  = mask + (size_t)b * 2048;

    if (tid < 32) flags[tid] = 0;
    __syncthreads();
    {
        uint2v mv = *(const uint2v*)&mb[tid * 8];
        if (mv[0] | mv[1]) flags[tid >> 3] = 1;
    }

    const int qrow = qt * 128 + wave * 32 + l31;
    bf16x8 qf[4];
#pragma unroll
    for (int ki = 0; ki < 4; ++ki)
        qf[ki] = *(const bf16x8*)&qh[(size_t)qrow * 64 + ki * 16 + hi * 8];

    // persistent zero C-operand and bf16 ones A-fragment
    const f32x16 zf = {0,0,0,0,0,0,0,0,0,0,0,0,0,0,0,0};
    bf16x8 ones;
#pragma unroll
    for (int j = 0; j < 8; ++j) ones[j] = (short)0x3F80;

    f32x16 accA = {0,0,0,0,0,0,0,0,0,0,0,0,0,0,0,0};
    f32x16 accB = {0,0,0,0,0,0,0,0,0,0,0,0,0,0,0,0};
    f32x16 accL = {0,0,0,0,0,0,0,0,0,0,0,0,0,0,0,0};  // only [0] is consumed
    float m_r = -1e30f;
    const float SC  = 0.18033688011112042f;            // 0.125 * log2(e)
    const float THR = 44.3614195558365f;               // 8 / SC  (defer-max)

    // async stage via global_load_lds: 512 chunks (8 ushorts) per tile per matrix.
    // LDS linear; source pre-swizzled so swizzled READ yields logical chunk (rule #21).
#define STAGE(KB, VB, KV0) do {                                                          \
        _Pragma("unroll")                                                                \
        for (int it_ = 0; it_ < 2; ++it_) {                                              \
            int c_ = it_ * 256 + tid;                                                    \
            int r_ = c_ >> 3, c8_ = c_ & 7;                                              \
            int sc8_ = c8_ ^ (r_ & 7);                                                   \
            gload_lds16(&kh[(size_t)((KV0) + r_) * 64 + sc8_ * 8],                       \
                        &(KB)[(it_ * 256 + wave * 64) * 8]);                             \
            gload_lds16(&vth[(size_t)r_ * 2048 + (KV0) + sc8_ * 8],                      \
                        &(VB)[(it_ * 256 + wave * 64) * 8]);                             \
        }                                                                                \
    } while (0)

    STAGE(smem, smem + 8192, t0 * 64);         // prologue -> buffer parity 0

    for (int t = t0; t < t0 + NT; ++t) {
        const int kv0 = t * 64;
        unsigned short* Kb = smem + ((t - t0) & 1) * 4096;
        unsigned short* Vb = smem + 8192 + ((t - t0) & 1) * 4096;
        __syncthreads();                       // drains vmcnt -> tile t staged; prev readers done
        if (t + 1 < t0 + NT) {
            unsigned short* Kn = smem + ((t + 1 - t0) & 1) * 4096;
            unsigned short* Vn = smem + 8192 + ((t + 1 - t0) & 1) * 4096;
            STAGE(Kn, Vn, kv0 + 64);           // prefetch next tile under compute
        }

        // ---- S^T = K @ Q^T (first mfma consumes persistent zero C) ----
        f32x16 s0, s1;
        __builtin_amdgcn_s_setprio(1);
        {
            int c0 = (hi ^ (l31 & 7)) * 8;
            bf16x8 a0 = *(const bf16x8*)&Kb[l31 * 64 + c0];
            bf16x8 a1 = *(const bf16x8*)&Kb[(32 + l31) * 64 + c0];
            s0 = mfma32(a0, qf[0], zf);
            s1 = mfma32(a1, qf[0], zf);
        }
#pragma unroll
        for (int ki = 1; ki < 4; ++ki) {
            int c0 = ((ki * 2 + hi) ^ (l31 & 7)) * 8;
            bf16x8 a0 = *(const bf16x8*)&Kb[l31 * 64 + c0];
            bf16x8 a1 = *(const bf16x8*)&Kb[(32 + l31) * 64 + c0];
            s0 = mfma32(a0, qf[ki], s0);
            s1 = mfma32(a1, qf[ki], s1);
        }
        __builtin_amdgcn_s_setprio(0);

        if (flags[t]) {
#pragma unroll
            for (int r = 0; r < 16; ++r) {
                int keyl = (r & 3) + 8 * (r >> 2) + 4 * hi;
                if (mb[kv0 + keyl])      s0[r] = -1e30f;
                if (mb[kv0 + 32 + keyl]) s1[r] = -1e30f;
            }
        }

        // ---- online softmax (max3 tree) ----
        float mx;
        {
            float a0 = m3(s0[0],  s0[1],  s0[2]);
            float a1 = m3(s0[3],  s0[4],  s0[5]);
            float a2 = m3(s0[6],  s0[7],  s0[8]);
            float a3 = m3(s0[9],  s0[10], s0[11]);
            float a4 = m3(s0[12], s0[13], s0[14]);
            float b0 = m3(s1[0],  s1[1],  s1[2]);
            float b1 = m3(s1[3],  s1[4],  s1[5]);
            float b2 = m3(s1[6],  s1[7],  s1[8]);
            float b3 = m3(s1[9],  s1[10], s1[11]);
            float b4 = m3(s1[12], s1[13], s1[14]);
            float c0 = m3(a0, a1, s0[15]);
            float c1 = m3(a2, a3, a4);
            float c2 = m3(b0, b1, s1[15]);
            float c3 = m3(b2, b3, b4);
            mx = fmaxf(m3(c0, c1, c2), c3);
        }
        mx = fmaxf(mx, __shfl_xor(mx, 32));
        if (__any(mx > m_r + THR)) {           // defer-max (T13)
            float mn  = fmaxf(m_r, mx);
            float scl = __builtin_amdgcn_exp2f((m_r - mn) * SC);
            m_r = mn;
            accL[0] *= scl;
#pragma unroll
            for (int i = 0; i < 16; ++i) { accA[i] *= scl; accB[i] *= scl; }
        }
        const float nmc = -m_r * SC;
#pragma unroll
        for (int i = 0; i < 16; ++i) {
            s0[i] = __builtin_amdgcn_exp2f(__builtin_fmaf(s0[i], SC, nmc));
            s1[i] = __builtin_amdgcn_exp2f(__builtin_fmaf(s1[i], SC, nmc));
        }

        // ---- P -> bf16 B-fragments (T12) ----
        bf16x8 pf[4];
        {
            union { unsigned int u[4]; bf16x8 v; } f;
            unsigned int w0 = cvtpk_bf16(s0[0],  s0[1]),  w1 = cvtpk_bf16(s0[2],  s0[3]);
            unsigned int w2 = cvtpk_bf16(s0[4],  s0[5]),  w3 = cvtpk_bf16(s0[6],  s0[7]);
            unsigned int w4 = cvtpk_bf16(s0[8],  s0[9]),  w5 = cvtpk_bf16(s0[10], s0[11]);
            unsigned int w6 = cvtpk_bf16(s0[12], s0[13]), w7 = cvtpk_bf16(s0[14], s0[15]);
            plswap(w0, w2); plswap(w1, w3); plswap(w4, w6); plswap(w5, w7);
            f.u[0] = w0; f.u[1] = w1; f.u[2] = w2; f.u[3] = w3; pf[0] = f.v;
            f.u[0] = w4; f.u[1] = w5; f.u[2] = w6; f.u[3] = w7; pf[1] = f.v;
            unsigned int x0 = cvtpk_bf16(s1[0],  s1[1]),  x1 = cvtpk_bf16(s1[2],  s1[3]);
            unsigned int x2 = cvtpk_bf16(s1[4],  s1[5]),  x3 = cvtpk_bf16(s1[6],  s1[7]);
            unsigned int x4 = cvtpk_bf16(s1[8],  s1[9]),  x5 = cvtpk_bf16(s1[10], s1[11]);
            unsigned int x6 = cvtpk_bf16(s1[12], s1[13]), x7 = cvtpk_bf16(s1[14], s1[15]);
            plswap(x0, x2); plswap(x1, x3); plswap(x4, x6); plswap(x5, x7);
            f.u[0] = x0; f.u[1] = x1; f.u[2] = x2; f.u[3] = x3; pf[2] = f.v;
            f.u[0] = x4; f.u[1] = x5; f.u[2] = x6; f.u[3] = x7; pf[3] = f.v;
        }

        // ---- ctx^T += V^T @ P^T ;  l += ones @ P^T (row-sum on MFMA pipe) ----
        __builtin_amdgcn_s_setprio(1);
#pragma unroll
        for (int ks = 0; ks < 4; ++ks) {
            int c0 = ((ks * 2 + hi) ^ (l31 & 7)) * 8;
            bf16x8 vA = *(const bf16x8*)&Vb[l31 * 64 + c0];
            bf16x8 vB = *(const bf16x8*)&Vb[(32 + l31) * 64 + c0];
            accA = mfma32(vA, pf[ks], accA);
            accB = mfma32(vB, pf[ks], accB);
            accL = mfma32(ones, pf[ks], accL);
        }
        __builtin_amdgcn_s_setprio(0);
    }
#undef STAGE

    // ---- epilogue: unnormalized bf16 partials + (m,l) ----
    __syncthreads();
    const int qloc = wave * 32 + l31;
#pragma unroll
    for (int r = 0; r < 16; ++r) {
        int dA = (r & 3) + 8 * (r >> 2) + 4 * hi;
        smem[qloc * 64 + (dA ^ ((qloc & 7) * 8))]        = f2bf(accA[r]);
        smem[qloc * 64 + ((32 + dA) ^ ((qloc & 7) * 8))] = f2bf(accB[r]);
    }
    if (hi == 0) {
        size_t mrow = ((size_t)half * 32 + bh) * 2048 + qt * 128 + qloc;
        *(float2*)&ml[mrow * 2] = make_float2(m_r, accL[0]);
    }
    __syncthreads();
    unsigned short* pdst = half ? part1 : part0;
    const size_t prow0 = (size_t)bh * 2048 + qt * 128;
#pragma unroll
    for (int it = 0; it < 4; ++it) {
        int idx = tid + it * 256;
        int q = idx >> 3, c = idx & 7;
        ushort8 vv = *(const ushort8*)&smem[q * 64 + ((c * 8) ^ ((q & 7) * 8))];
        *(ushort8*)&pdst[(prow0 + q) * 64 + c * 8] = vv;
    }
}

// ---------------- split-KV combine ----------------

__global__ void combine_kernel(const unsigned short* __restrict__ part0,
                               const unsigned short* __restrict__ part1,
                               const float* __restrict__ ml,
                               unsigned short* __restrict__ ctxb)
{
    const float SC = 0.18033688011112042f;
    int gid = blockIdx.x * 256 + threadIdx.x;          // 65536 rows * 8 chunks
    int row = gid >> 3, c = gid & 7;
    ushort8 v0 = *(const ushort8*)&part0[(size_t)row * 64 + c * 8];
    ushort8 v1 = *(const ushort8*)&part1[(size_t)row * 64 + c * 8];
    float2 a = *(const float2*)&ml[(size_t)row * 2];
    float2 d = *(const float2*)&ml[(size_t)(65536 + row) * 2];
    float m  = fmaxf(a.x, d.x);
    float w0 = __builtin_amdgcn_exp2f((a.x - m) * SC);
    float w1 = __builtin_amdgcn_exp2f((d.x - m) * SC);
    float li = 1.0f / (a.y * w0 + d.y * w1);
    ushort8 o;
#pragma unroll
    for (int j = 0; j < 8; ++j)
        o[j] = f2bf((bf2f(v0[j]) * w0 + bf2f(v1[j]) * w1) * li);
    int bh = row >> 11, ql = row & 2047;
    int bb = bh >> 4, hh = bh & 15;
    *(ushort8*)&ctxb[((size_t)(bb * 2048 + ql)) * 1024 + hh * 64 + c * 8] = o;
}

// ---------------- launch ----------------

extern "C" void kernel_launch(void* const* d_in, const int* in_sizes, int n_in,
                              void* d_out, int out_size, void* d_ws, size_t ws_size,
                              hipStream_t stream)
{
    const float* x  = (const float*)d_in[0];
    const float* wq = (const float*)d_in[1];
    const float* wk = (const float*)d_in[2];
    const float* wv = (const float*)d_in[3];
    const float* wo = (const float*)d_in[4];
    const unsigned char* mask = (const unsigned char*)d_in[5];
    float* out = (float*)d_out;

    char* ws = (char*)d_ws;
    unsigned short* xb   = (unsigned short*)(ws);                 //  8 MB  [4096][1024]
    unsigned short* wpT  = (unsigned short*)(ws + 8388608);       //  6 MB  [3072][1024]
    unsigned short* woT  = (unsigned short*)(ws + 14680064);      //  2 MB  [1024][1024]
    unsigned short* qb   = (unsigned short*)(ws + 16777216);      //  8 MB  [32][2048][64]
    unsigned short* kb   = (unsigned short*)(ws + 25165824);      //  8 MB  [32][2048][64]
    unsigned short* vtb  = (unsigned short*)(ws + 33554432);      //  8 MB  [32][64][2048] (V^T, written by gemm<0>)
    unsigned short* ctxb = (unsigned short*)(ws + 41943040);      //  8 MB  [4096][1024]
    // scratch reuse (stream-ordered, race-free):
    //   part0/part1 live in d_out (16 MB), overwritten by the final gemm<1>;
    //   ml overlays wpT (dead after gemm<0>).
    unsigned short* part0 = (unsigned short*)d_out;               //  8 MB
    unsigned short* part1 = (unsigned short*)d_out + 4194304;     //  8 MB
    float*          mlb   = (float*)wpT;                          //  1 MB

    cast_x_kernel<<<4096, 256, 0, stream>>>(x, xb);
    pack_wqkv_t  <<<dim3(16, 48), 256, 0, stream>>>(wq, wk, wv, wpT);
    pack_wo_t    <<<dim3(16, 16), 256, 0, stream>>>(wo, woT);

    gemm_bt<0,128><<<dim3(24, 32), 256, 0, stream>>>(xb, wpT, nullptr, qb, kb, vtb, 4096, 3072, 1024);

    attn_kernel<<<1024, 256, 0, stream>>>(qb, kb, vtb, mask, part0, part1, mlb);
    combine_kernel<<<2048, 256, 0, stream>>>(part0, part1, mlb, ctxb);

    gemm_bt<1,64><<<dim3(16, 32), 256, 0, stream>>>(ctxb, woT, out, nullptr, nullptr, nullptr, 4096, 1024, 1024);
}